// Round 7
// baseline (404.440 us; speedup 1.0000x reference)
//
#include <hip/hip_runtime.h>
#include <hip/hip_bf16.h>
#include <math.h>

// ---------------------------------------------------------------------------
// VAE ELBO (chromatin VAE). Sizes fixed by the reference.
//
//  * NB_ENC == NB_DEC == 16, identical binning => ONE nibble histogram serves
//    both the encoder input (log1p counts) and the mixture likelihood.
//  * r3-r5 (3x replicated): global atomics on gfx950 are memory-side ~32B
//    RMW each regardless of scope/footprint => NO per-record global atomics.
//    Two-phase LDS counting sort builds hist/frag (r6: 154us -> ~30us).
//  * r6: old fused decoder was s_load-latency-bound (VALUBusy 33%): the
//    1000x [1024x50]x[50x16] logits batch is now bf16 MFMA (16x16x32, K
//    padded to 64 with zeros); softmax over components = shfl_xor across the
//    16 lanes of a quad-group (D: col=lane&15=n, row=quad*4+reg=cell).
//    Poisson split into its own kernel with a log-factorial LUT (no lgammaf).
//  * All sums -> one f64 accumulator; N_CUTS*log(16) folded at finalize.
// ---------------------------------------------------------------------------

#define G_      1000
#define C_      1024
#define L_      50
#define K_      16
#define NHID_   16
#define CUT_SCALE   12.5f          // N_TOTAL_CUTS / N_CUTS
#define CELL_SCALE  9.765625f      // N_TOTAL_CELLS / N_CELLS

#define NCHUNK_   500              // encoder partial chunks
#define RCAP_CUT  18432            // bucket capacity, cuts  (mean 16000)
#define RCAP_FRAG 9216             // bucket capacity, frags (mean 8000)

// ws layout (bytes). [0, ZERO_BYTES) memset each call (covers bf16 pads).
#define CTL_OFF    0ull            // gcnt_c[256] | gcnt_f[256] | acc | bnsum[32]
#define LATBF_OFF  2560ull         // bf16 [1024][64]  cell-major latent, pad 0
#define LWT_OFF    133632ull       // bf16 [1000][16][64]  lw^T, k-pad 0
#define ZERO_BYTES 2181632ull
#define ENTC_OFF   2181632ull      // u16 [256][18432]
#define ENTF_OFF   11618816ull     // u16 [256][9216]
#define MERGED_OFF 16337408ull     // u32 [16000][128] nibble hist
#define FRAGU8_OFF 24529408ull     // u8  [1000][1024]
#define P_OFF      25553408ull     // f32 [500][16][1024]
#define HT_OFF     58321408ull     // f32 [16][1024]
#define LATT_OFF   58386944ull     // f32 [50][1024]
#define WS_NEED    58591744ull

typedef __attribute__((ext_vector_type(8))) short short8;
typedef __attribute__((ext_vector_type(4))) float f32x4;

__device__ __constant__ float LGT[32] = {   // log(n!)
    0.0f, 0.0f, 0.6931471805599453f, 1.791759469228055f, 3.1780538303479458f,
    4.787491742782046f, 6.579251212010101f, 8.525161361065415f,
    10.60460290274525f, 12.801827480081469f, 15.104412573075516f,
    17.502307845873887f, 19.987214495661885f, 22.552163853123425f,
    25.19122118273868f, 27.89927138384089f, 30.671860106080672f,
    33.50507345013689f, 36.39544520803305f, 39.339884187199495f,
    42.335616460753485f, 45.38013889847691f, 48.47118135183523f,
    51.60667556776438f, 54.78472939811232f, 58.00360522298052f,
    61.261701761002f, 64.55753862700633f, 67.88974313718154f,
    71.25703896716801f, 74.65823634883016f, 78.0922235533153f };

__device__ __forceinline__ float block_sum_256(float v) {
    __shared__ float sm[256];
    int t = threadIdx.x;
    __syncthreads();
    sm[t] = v;
    __syncthreads();
#pragma unroll
    for (int s = 128; s > 0; s >>= 1) {
        if (t < s) sm[t] += sm[t + s];
        __syncthreads();
    }
    return sm[0];
}

// --- 1. radix partition into 256 buckets (MODE 0 = cuts, 1 = frags) --------
template<int MODE>
__global__ __launch_bounds__(256)
void part_kernel(const int* __restrict__ idx,
                 const float* __restrict__ coord,   // unused for MODE 1
                 unsigned int* __restrict__ gcount,
                 unsigned short* __restrict__ ent,
                 int n, int rcap) {
    __shared__ unsigned int cnt[256], excl[256], cur[256], gbase_s[256];
    __shared__ unsigned short stage[4096];
    __shared__ unsigned char bkof[4096];
    int t = threadIdx.x;
    int i0 = blockIdx.x * 4096;
    unsigned char mybk[16];
    unsigned short myent[16];
    bool myval[16];
    cnt[t] = 0;
    __syncthreads();
#pragma unroll
    for (int k = 0; k < 16; ++k) {
        int i = i0 + k * 256 + t;
        bool v = (i < n);
        unsigned int bk = 0; unsigned short e = 0;
        if (v) {
            int ix = idx[i];
            int c = ix / G_;
            int g = ix - c * G_;
            if (MODE == 0) {
                float x = coord[i];
                int b = (int)(x * 16.0f); b = b > 15 ? 15 : b;
                int bin = g * K_ + b;
                bk = ((unsigned)(c >> 6) << 4) | ((unsigned)bin >> 10);
                e = (unsigned short)(((c & 63) << 10) | (bin & 1023));
            } else {
                bk = ((unsigned)(c >> 6) << 4) | ((unsigned)g >> 6);
                e = (unsigned short)(((c & 63) << 6) | (g & 63));
            }
            atomicAdd(&cnt[bk], 1u);   // LDS atomic
        }
        mybk[k] = (unsigned char)bk; myent[k] = e; myval[k] = v;
    }
    __syncthreads();
    excl[t] = cnt[t];
    __syncthreads();
    for (int o = 1; o < 256; o <<= 1) {
        unsigned int v = (t >= o) ? excl[t - o] : 0u;
        __syncthreads();
        excl[t] += v;
        __syncthreads();
    }
    unsigned int my_excl = excl[t] - cnt[t];
    gbase_s[t] = cnt[t] ? atomicAdd(&gcount[t], cnt[t]) : 0u;  // global reserve
    cur[t] = my_excl;
    __syncthreads();
    excl[t] = my_excl;
    __syncthreads();
#pragma unroll
    for (int k = 0; k < 16; ++k) {
        if (myval[k]) {
            unsigned int p = atomicAdd(&cur[mybk[k]], 1u);   // LDS atomic
            stage[p] = myent[k];
            bkof[p] = mybk[k];
        }
    }
    __syncthreads();
    unsigned int total = excl[255] + cnt[255];
    for (unsigned int p = t; p < total; p += 256) {
        unsigned int bk = bkof[p];
        unsigned int dst = gbase_s[bk] + (p - excl[bk]);
        if (dst < (unsigned)rcap)
            ent[(size_t)bk * rcap + dst] = stage[p];
    }
}

// --- 2a. per-bucket cut histogram: LDS nibbles -> sector-exclusive store ---
__global__ __launch_bounds__(256)
void hist2_kernel(const unsigned int* __restrict__ gcount,
                  const unsigned short* __restrict__ ent,
                  unsigned int* __restrict__ merged) {  // [16000][128] words
    __shared__ unsigned int h[8192];   // 1024 bins x 8 words (64 cells nibble)
    int t = threadIdx.x;
    int bk = blockIdx.x;
    int cg = bk >> 4, bc = bk & 15;
    for (int i = t; i < 8192; i += 256) h[i] = 0;
    __syncthreads();
    unsigned int count = gcount[bk];
    if (count > RCAP_CUT) count = RCAP_CUT;
    const unsigned short* e = ent + (size_t)bk * RCAP_CUT;
    for (unsigned int p = t; p < count; p += 256) {
        unsigned int v = e[p];
        unsigned int bin_lo = v & 1023u;
        unsigned int c_lo = v >> 10;
        atomicAdd(&h[bin_lo * 8 + (c_lo >> 3)], 1u << ((c_lo & 7) * 4));
    }
    __syncthreads();
    for (int i = t; i < 8192; i += 256) {
        int bin = bc * 1024 + (i >> 3);
        if (bin < 16000)
            merged[(unsigned)bin * 128u + (unsigned)cg * 8u + (i & 7)] = h[i];
    }
}

// --- 2b. per-bucket frag counts: LDS u16 -> u8 sector-exclusive store ------
__global__ __launch_bounds__(256)
void frag2_kernel(const unsigned int* __restrict__ gcount,
                  const unsigned short* __restrict__ ent,
                  unsigned int* __restrict__ fragw) {   // u8[1000][1024] as u32
    __shared__ unsigned int f[2048];   // 64 g x 32 words (2 u16 cells/word)
    int t = threadIdx.x;
    int bk = blockIdx.x;
    int cg = bk >> 4, gc = bk & 15;
    for (int i = t; i < 2048; i += 256) f[i] = 0;
    __syncthreads();
    unsigned int count = gcount[bk];
    if (count > RCAP_FRAG) count = RCAP_FRAG;
    const unsigned short* e = ent + (size_t)bk * RCAP_FRAG;
    for (unsigned int p = t; p < count; p += 256) {
        unsigned int v = e[p];
        unsigned int g_lo = v & 63u;
        unsigned int c_lo = v >> 6;
        atomicAdd(&f[g_lo * 32 + (c_lo >> 1)], 1u << ((c_lo & 1) * 16));
    }
    __syncthreads();
    for (int i = t; i < 1024; i += 256) {  // 64 g x 16 output words
        int g_lo = i >> 4, wb = i & 15;
        unsigned int lo = f[g_lo * 32 + wb * 2];
        unsigned int hi = f[g_lo * 32 + wb * 2 + 1];
        unsigned int out = (lo & 0xffu) | (((lo >> 16) & 0xffu) << 8)
                         | ((hi & 0xffu) << 16) | (((hi >> 16) & 0xffu) << 24);
        int g = gc * 64 + g_lo;
        if (g < G_)
            fragw[(unsigned)g * 256u + (unsigned)cg * 16u + wb] = out;
    }
}

// --- 3. encoder matmul from merged hist ------------------------------------
__global__ __launch_bounds__(256)
void enc_kernel(const unsigned int* __restrict__ merged, // [16000][128]
                const float* __restrict__ W1,            // [16000][16]
                float* __restrict__ P) {                 // [500][16][1024]
    int t = threadIdx.x;
    int w = t & 127;
    int rl = t >> 7;
    int row0 = blockIdx.x * 32;
    float acc[NHID_][8];
#pragma unroll
    for (int j = 0; j < NHID_; ++j)
#pragma unroll
        for (int u = 0; u < 8; ++u) acc[j][u] = 0.f;
    for (int it = 0; it < 16; ++it) {
        int row = row0 + it * 2 + rl;
        unsigned int mw = merged[(unsigned)row * 128u + (unsigned)w];
        float xv[8];
#pragma unroll
        for (int u = 0; u < 8; ++u)
            xv[u] = __logf((float)(((mw >> (u * 4)) & 0xfu) + 1u));
        const float* wr = W1 + (size_t)row * NHID_;   // wave-uniform -> s_load
#pragma unroll
        for (int j = 0; j < NHID_; ++j) {
            float wj = wr[j];
#pragma unroll
            for (int u = 0; u < 8; ++u) acc[j][u] = fmaf(xv[u], wj, acc[j][u]);
        }
    }
    __shared__ float sp[NHID_][128][8];   // 64 KB
    if (rl == 1) {
#pragma unroll
        for (int j = 0; j < NHID_; ++j)
#pragma unroll
            for (int u = 0; u < 8; ++u) sp[j][w][u] = acc[j][u];
    }
    __syncthreads();
    if (rl == 0) {
        float* Pp = P + (size_t)blockIdx.x * (NHID_ * C_) + (w * 8);
#pragma unroll
        for (int j = 0; j < NHID_; ++j)
#pragma unroll
            for (int u = 0; u < 8; ++u)
                Pp[j * C_ + u] = acc[j][u] + sp[j][w][u];
    }
}

// --- 4. reduce partials -> hT[j][c]; f64 BN sums ---------------------------
__global__ __launch_bounds__(64)
void bn_kernel(const float* __restrict__ P,
               float* __restrict__ hT,
               double* __restrict__ bnsum) {  // [0..15]=sum, [16..31]=sumsq
    int j = blockIdx.x;
    int c = blockIdx.y * 64 + threadIdx.x;
    float s = 0.f;
#pragma unroll 8
    for (int ch = 0; ch < NCHUNK_; ++ch)
        s += P[((size_t)ch * NHID_ + j) * C_ + c];
    hT[j * C_ + c] = s;
    float s1 = s, s2 = s * s;
#pragma unroll
    for (int o = 32; o > 0; o >>= 1) {
        s1 += __shfl_down(s1, o);
        s2 += __shfl_down(s2, o);
    }
    if (threadIdx.x == 0) {
        atomicAdd(&bnsum[j], (double)s1);
        atomicAdd(&bnsum[NHID_ + j], (double)s2);
    }
}

// --- 4b. lw -> bf16 transposed [g][n][64] (k-pad zeroed by memset) ---------
__global__ __launch_bounds__(256)
void lwprep_kernel(const float* __restrict__ lw,      // [1000][50][16]
                   __hip_bfloat16* __restrict__ lwT) { // [1000][16][64]
    int g = blockIdx.x;
    for (int r = threadIdx.x; r < L_ * K_; r += 256) {
        float v = lw[(size_t)g * (L_ * K_) + r];
        lwT[(size_t)g * 1024 + (r & 15) * 64 + (r >> 4)] = __float2bfloat16(v);
    }
}

// --- 5. latent sample + latent KL; writes latT f32 + latbf bf16 ------------
__global__ __launch_bounds__(256)
void latent_kernel(const float* __restrict__ hT,
                   const double* __restrict__ bnsum,
                   const float* __restrict__ gamma,
                   const float* __restrict__ beta,
                   const float* __restrict__ W_loc,   // [16][50]
                   const float* __restrict__ b_loc,
                   const float* __restrict__ W_scale, // [16][50]
                   const float* __restrict__ b_scale,
                   const float* __restrict__ eps,     // [1024][50]
                   float* __restrict__ latT,          // [50][1024]
                   __hip_bfloat16* __restrict__ latbf,// [1024][64] pad 0
                   double* __restrict__ acc) {
    int idx = blockIdx.x * 256 + threadIdx.x;
    float kl = 0.f;
    if (idx < C_ * L_) {
        int c = idx / L_;
        int l = idx - c * L_;
        float hb[NHID_];
#pragma unroll
        for (int j = 0; j < NHID_; ++j) {
            float mean = (float)(bnsum[j] * (1.0 / C_));
            float ex2  = (float)(bnsum[NHID_ + j] * (1.0 / C_));
            float var = ex2 - mean * mean;
            float rstd = rsqrtf(var + 1e-5f);
            float sc = gamma[j] * rstd;
            float sh = beta[j] - mean * sc;
            float v = fmaf(hT[j * C_ + c], sc, sh);
            hb[j] = v > 0.f ? v : 0.f;
        }
        float loc = b_loc[l], ls = b_scale[l];
#pragma unroll
        for (int j = 0; j < NHID_; ++j) {
            loc = fmaf(hb[j], W_loc[j * L_ + l], loc);
            ls  = fmaf(hb[j], W_scale[j * L_ + l], ls);
        }
        float qs = 0.1f * __expf(ls);
        float e = eps[idx];
        float lat = fmaf(qs, e, loc);
        latT[(size_t)l * C_ + c] = lat;
        latbf[c * 64 + l] = __float2bfloat16(lat);
        float z = (lat - loc) / qs;
        kl = fmaf(-0.5f * lat, lat, fmaf(0.5f * z, z, __logf(qs)));
    }
    float s = block_sum_256(kl);
    if (threadIdx.x == 0) atomicAdd(acc, -(double)(CELL_SCALE * s));
}

// --- 6. weight KL (logit_weight + rho_weight), N(0,0.1) --------------------
__global__ __launch_bounds__(256)
void wkl_kernel(const float* __restrict__ lw,
                const float* __restrict__ rw,
                double* __restrict__ acc) {
    const int NTOT = G_ * L_ * K_ + G_ * L_;   // 850000
    float s = 0.f;
    for (int i = blockIdx.x * 256 + threadIdx.x; i < NTOT; i += gridDim.x * 256) {
        float w = (i < G_ * L_ * K_) ? lw[i] : rw[i - G_ * L_ * K_];
        s += fmaf(-50.f * w, w, 1.3836465597893733f);
    }
    s = block_sum_256(s);
    if (threadIdx.x == 0) atomicAdd(acc, -(double)s);
}

// --- 7a. mixture likelihood via bf16 MFMA ----------------------------------
// grid (1000 genes, 4 cell-tiles) x 256 (4 waves); wave: 64 cells as 4
// m-tiles of 16. D-layout: col=lane&15=n (component), row=quad*4+reg=cell.
__global__ __launch_bounds__(256)
void mix_kernel(const __hip_bfloat16* __restrict__ latbf, // [1024][64]
                const __hip_bfloat16* __restrict__ lwT,   // [1000][16][64]
                const unsigned int* __restrict__ merged,  // [16000][128]
                const float* __restrict__ baseline,       // [1000][16]
                double* __restrict__ acc) {
    int g = blockIdx.x;
    int lane = threadIdx.x & 63;
    int wv = threadIdx.x >> 6;
    int n = lane & 15;
    int quad = lane >> 4;
    const __hip_bfloat16* bb = lwT + (size_t)g * 1024 + n * 64 + quad * 8;
    short8 b1 = *(const short8*)bb;
    short8 b2 = *(const short8*)(bb + 32);
    float bl = baseline[g * K_ + n];
    float partial = 0.f;
    int cwave = blockIdx.y * 256 + wv * 64;
#pragma unroll
    for (int mt = 0; mt < 4; ++mt) {
        int c0 = cwave + mt * 16;
        const __hip_bfloat16* aa = latbf + (size_t)(c0 + n) * 64 + quad * 8;
        short8 a1 = *(const short8*)aa;
        short8 a2 = *(const short8*)(aa + 32);
        f32x4 d = {bl, bl, bl, bl};
        d = __builtin_amdgcn_mfma_f32_16x16x32_bf16(a1, b1, d, 0, 0, 0);
        d = __builtin_amdgcn_mfma_f32_16x16x32_bf16(a2, b2, d, 0, 0, 0);
        // softmax over n: shfl_xor across the 16 lanes of this quad-group
        float mx[4], ex[4];
#pragma unroll
        for (int r = 0; r < 4; ++r) mx[r] = d[r];
#pragma unroll
        for (int m = 1; m < 16; m <<= 1)
#pragma unroll
            for (int r = 0; r < 4; ++r) mx[r] = fmaxf(mx[r], __shfl_xor(mx[r], m));
#pragma unroll
        for (int r = 0; r < 4; ++r) ex[r] = __expf(d[r] - mx[r]);
#pragma unroll
        for (int m = 1; m < 16; m <<= 1)
#pragma unroll
            for (int r = 0; r < 4; ++r) ex[r] += __shfl_xor(ex[r], m);
        int cp = c0 + quad * 4;
        unsigned int hw = merged[(unsigned)(g * K_ + n) * 128u + ((unsigned)cp >> 3)];
        int sb = (cp & 7) * 4;
#pragma unroll
        for (int r = 0; r < 4; ++r) {
            float lse = mx[r] + __logf(ex[r]);
            float cnt = (float)((hw >> (sb + r * 4)) & 0xfu);
            partial = fmaf(cnt, d[r] - lse, partial);
        }
    }
    float s = block_sum_256(-CUT_SCALE * partial);
    if (threadIdx.x == 0) atomicAdd(acc, (double)s);
}

// --- 7b. Poisson fragment likelihood ---------------------------------------
__global__ __launch_bounds__(256)
void pois_kernel(const float* __restrict__ latT,          // [50][1024]
                 const float* __restrict__ rw,            // [1000][50]
                 const float* __restrict__ rho_bias,
                 const int* __restrict__ libsize,
                 const unsigned char* __restrict__ fragb, // [1000][1024]
                 double* __restrict__ acc) {
    int g = blockIdx.x;
    int c = blockIdx.y * 256 + threadIdx.x;
    const float* rwg = rw + (size_t)g * L_;   // hoists to SGPRs
    float rho = 0.f;
#pragma unroll 10
    for (int l = 0; l < L_; ++l)
        rho = fmaf(latT[l * C_ + c], rwg[l], rho);
    unsigned int fc = fragb[(size_t)g * C_ + c];
    float fe = rho_bias[g] * __expf(rho) * (float)libsize[c];
    float lf = fmaf((float)fc, __logf(fe), -fe) - LGT[fc > 31u ? 31u : fc];
    float s = block_sum_256(-CELL_SCALE * lf);
    if (threadIdx.x == 0) atomicAdd(acc, (double)s);
}

// --- 8. finalize -----------------------------------------------------------
__global__ void final_kernel(const double* __restrict__ acc, float* __restrict__ out) {
    // -12.5 * 4e6 * log(16)
    out[0] = (float)(acc[0] - 138629436.11198905);
}

extern "C" void kernel_launch(void* const* d_in, const int* in_sizes, int n_in,
                              void* d_out, int out_size, void* d_ws, size_t ws_size,
                              hipStream_t stream) {
    const float* cut_coord = (const float*)d_in[0];
    const float* eps       = (const float*)d_in[1];
    const float* enc_W1    = (const float*)d_in[2];
    // d_in[3] = enc_b1 : cancels through BatchNorm, unused
    const float* bn_gamma  = (const float*)d_in[4];
    const float* bn_beta   = (const float*)d_in[5];
    const float* W_loc     = (const float*)d_in[6];
    const float* b_loc     = (const float*)d_in[7];
    const float* W_scale   = (const float*)d_in[8];
    const float* b_scale   = (const float*)d_in[9];
    const float* logit_w   = (const float*)d_in[10];
    const float* rho_w     = (const float*)d_in[11];
    const float* baseline  = (const float*)d_in[12];
    const float* rho_bias  = (const float*)d_in[13];
    const int* cut_cxg     = (const int*)d_in[14];
    const int* frag_ix     = (const int*)d_in[16];
    const int* libsize     = (const int*)d_in[19];

    int n_cuts  = in_sizes[0];
    int n_frags = in_sizes[16];

    char* ws = (char*)d_ws;
    unsigned int*  gcnt_c  = (unsigned int*)(ws + CTL_OFF);
    unsigned int*  gcnt_f  = (unsigned int*)(ws + CTL_OFF + 1024);
    double*        acc     = (double*)(ws + CTL_OFF + 2048);
    double*        bnsum   = (double*)(ws + CTL_OFF + 2056);
    __hip_bfloat16* latbf  = (__hip_bfloat16*)(ws + LATBF_OFF);
    __hip_bfloat16* lwT    = (__hip_bfloat16*)(ws + LWT_OFF);
    unsigned short* entc   = (unsigned short*)(ws + ENTC_OFF);
    unsigned short* entf   = (unsigned short*)(ws + ENTF_OFF);
    unsigned int*  merged  = (unsigned int*)(ws + MERGED_OFF);
    unsigned int*  fragw   = (unsigned int*)(ws + FRAGU8_OFF);
    float*         P       = (float*)(ws + P_OFF);
    float*         hT      = (float*)(ws + HT_OFF);
    float*         latT    = (float*)(ws + LATT_OFF);
    float*         out     = (float*)d_out;

    hipMemsetAsync(ws, 0, ZERO_BYTES, stream);

    part_kernel<0><<<(n_cuts + 4095) / 4096, 256, 0, stream>>>(
        cut_cxg, cut_coord, gcnt_c, entc, n_cuts, RCAP_CUT);
    part_kernel<1><<<(n_frags + 4095) / 4096, 256, 0, stream>>>(
        frag_ix, (const float*)nullptr, gcnt_f, entf, n_frags, RCAP_FRAG);
    hist2_kernel<<<256, 256, 0, stream>>>(gcnt_c, entc, merged);
    frag2_kernel<<<256, 256, 0, stream>>>(gcnt_f, entf, fragw);
    lwprep_kernel<<<G_, 256, 0, stream>>>(logit_w, lwT);
    enc_kernel<<<NCHUNK_, 256, 0, stream>>>(merged, enc_W1, P);
    bn_kernel<<<dim3(16, 16), 64, 0, stream>>>(P, hT, bnsum);
    latent_kernel<<<(C_ * L_ + 255) / 256, 256, 0, stream>>>(
        hT, bnsum, bn_gamma, bn_beta, W_loc, b_loc, W_scale, b_scale,
        eps, latT, latbf, acc);
    wkl_kernel<<<512, 256, 0, stream>>>(logit_w, rho_w, acc);
    mix_kernel<<<dim3(G_, 4), 256, 0, stream>>>(latbf, lwT, merged, baseline, acc);
    pois_kernel<<<dim3(G_, 4), 256, 0, stream>>>(latT, rho_w, rho_bias,
                                                 libsize, (const unsigned char*)fragw, acc);
    final_kernel<<<1, 1, 0, stream>>>(acc, out);
}

// Round 8
// 328.900 us; speedup vs baseline: 1.2297x; 1.2297x over previous
//
#include <hip/hip_runtime.h>
#include <hip/hip_bf16.h>
#include <math.h>

// ---------------------------------------------------------------------------
// VAE ELBO (chromatin VAE). Sizes fixed by the reference.
//
//  * NB_ENC == NB_DEC == 16, identical binning => ONE nibble histogram serves
//    both the encoder input (log1p counts) and the mixture likelihood.
//  * r3-r5 (3x replicated): global atomics on gfx950 are memory-side ~32B
//    RMW each regardless of scope/footprint => NO per-record global atomics.
//    Two-phase LDS counting sort builds hist/frag.
//  * r7 lesson: SAME-ADDRESS atomics serialize at ~16 ns each — 4000
//    per-block atomicAdd(acc) made every (1000,4)-grid kernel cost ~64 us
//    regardless of body (old scalar main and MFMA mix both 64 us, all pipes
//    idle). Fix: blocks write f32 partials (plain stores, fully written
//    every call); final_kernel f64-reduces all 8712 partials in one block.
//  * Mixture logits = bf16 MFMA 16x16x32 (K padded 50->64 with zeros);
//    softmax over components = shfl_xor across the 16 lanes of a quad-group
//    (D: col=lane&15=n, row=quad*4+reg=cell). Poisson uses log-factorial LUT.
// ---------------------------------------------------------------------------

#define G_      1000
#define C_      1024
#define L_      50
#define K_      16
#define NHID_   16
#define CUT_SCALE   12.5f          // N_TOTAL_CUTS / N_CUTS
#define CELL_SCALE  9.765625f      // N_TOTAL_CELLS / N_CELLS

#define NCHUNK_   500              // encoder partial chunks
#define RCAP_CUT  18432            // bucket capacity, cuts  (mean 16000)
#define RCAP_FRAG 9216             // bucket capacity, frags (mean 8000)

// partial-sum buffer layout (f32), all fully written each call:
//   [0,4000) mix | [4000,8000) pois | [8000,8512) wkl | [8512,8712) latent
#define NPB_MIX  4000
#define NPB_POIS 4000
#define NPB_WKL  512
#define NPB_LAT  200
#define NPB_TOT  8712

// ws layout (bytes). [0, ZERO_BYTES) memset each call (covers bf16 pads).
#define CTL_OFF    0ull            // gcnt_c[256] | gcnt_f[256] | bnsum[32] f64
#define LATBF_OFF  2560ull         // bf16 [1024][64]  cell-major latent, pad 0
#define LWT_OFF    133632ull       // bf16 [1000][16][64]  lw^T, k-pad 0
#define ZERO_BYTES 2181632ull
#define ENTC_OFF   2181632ull      // u16 [256][18432]
#define ENTF_OFF   11618816ull     // u16 [256][9216]
#define MERGED_OFF 16337408ull     // u32 [16000][128] nibble hist
#define FRAGU8_OFF 24529408ull     // u8  [1000][1024]
#define P_OFF      25553408ull     // f32 [500][16][1024]
#define HT_OFF     58321408ull     // f32 [16][1024]
#define LATT_OFF   58386944ull     // f32 [50][1024]
#define PB_OFF     58591744ull     // f32 [8712] partials
#define WS_NEED    58626592ull

typedef __attribute__((ext_vector_type(8))) short short8;
typedef __attribute__((ext_vector_type(4))) float f32x4;

__device__ __constant__ float LGT[32] = {   // log(n!)
    0.0f, 0.0f, 0.6931471805599453f, 1.791759469228055f, 3.1780538303479458f,
    4.787491742782046f, 6.579251212010101f, 8.525161361065415f,
    10.60460290274525f, 12.801827480081469f, 15.104412573075516f,
    17.502307845873887f, 19.987214495661885f, 22.552163853123425f,
    25.19122118273868f, 27.89927138384089f, 30.671860106080672f,
    33.50507345013689f, 36.39544520803305f, 39.339884187199495f,
    42.335616460753485f, 45.38013889847691f, 48.47118135183523f,
    51.60667556776438f, 54.78472939811232f, 58.00360522298052f,
    61.261701761002f, 64.55753862700633f, 67.88974313718154f,
    71.25703896716801f, 74.65823634883016f, 78.0922235533153f };

__device__ __forceinline__ float block_sum_256(float v) {
    __shared__ float sm[256];
    int t = threadIdx.x;
    __syncthreads();
    sm[t] = v;
    __syncthreads();
#pragma unroll
    for (int s = 128; s > 0; s >>= 1) {
        if (t < s) sm[t] += sm[t + s];
        __syncthreads();
    }
    return sm[0];
}

// --- 1. radix partition into 256 buckets (MODE 0 = cuts, 1 = frags) --------
template<int MODE>
__global__ __launch_bounds__(256)
void part_kernel(const int* __restrict__ idx,
                 const float* __restrict__ coord,   // unused for MODE 1
                 unsigned int* __restrict__ gcount,
                 unsigned short* __restrict__ ent,
                 int n, int rcap) {
    __shared__ unsigned int cnt[256], excl[256], cur[256], gbase_s[256];
    __shared__ unsigned short stage[4096];
    __shared__ unsigned char bkof[4096];
    int t = threadIdx.x;
    int i0 = blockIdx.x * 4096;
    unsigned char mybk[16];
    unsigned short myent[16];
    bool myval[16];
    cnt[t] = 0;
    __syncthreads();
#pragma unroll
    for (int k = 0; k < 16; ++k) {
        int i = i0 + k * 256 + t;
        bool v = (i < n);
        unsigned int bk = 0; unsigned short e = 0;
        if (v) {
            int ix = idx[i];
            int c = ix / G_;
            int g = ix - c * G_;
            if (MODE == 0) {
                float x = coord[i];
                int b = (int)(x * 16.0f); b = b > 15 ? 15 : b;
                int bin = g * K_ + b;
                bk = ((unsigned)(c >> 6) << 4) | ((unsigned)bin >> 10);
                e = (unsigned short)(((c & 63) << 10) | (bin & 1023));
            } else {
                bk = ((unsigned)(c >> 6) << 4) | ((unsigned)g >> 6);
                e = (unsigned short)(((c & 63) << 6) | (g & 63));
            }
            atomicAdd(&cnt[bk], 1u);   // LDS atomic
        }
        mybk[k] = (unsigned char)bk; myent[k] = e; myval[k] = v;
    }
    __syncthreads();
    excl[t] = cnt[t];
    __syncthreads();
    for (int o = 1; o < 256; o <<= 1) {
        unsigned int v = (t >= o) ? excl[t - o] : 0u;
        __syncthreads();
        excl[t] += v;
        __syncthreads();
    }
    unsigned int my_excl = excl[t] - cnt[t];
    gbase_s[t] = cnt[t] ? atomicAdd(&gcount[t], cnt[t]) : 0u;  // global reserve
    cur[t] = my_excl;
    __syncthreads();
    excl[t] = my_excl;
    __syncthreads();
#pragma unroll
    for (int k = 0; k < 16; ++k) {
        if (myval[k]) {
            unsigned int p = atomicAdd(&cur[mybk[k]], 1u);   // LDS atomic
            stage[p] = myent[k];
            bkof[p] = mybk[k];
        }
    }
    __syncthreads();
    unsigned int total = excl[255] + cnt[255];
    for (unsigned int p = t; p < total; p += 256) {
        unsigned int bk = bkof[p];
        unsigned int dst = gbase_s[bk] + (p - excl[bk]);
        if (dst < (unsigned)rcap)
            ent[(size_t)bk * rcap + dst] = stage[p];
    }
}

// --- 2a. per-bucket cut histogram: LDS nibbles -> sector-exclusive store ---
__global__ __launch_bounds__(256)
void hist2_kernel(const unsigned int* __restrict__ gcount,
                  const unsigned short* __restrict__ ent,
                  unsigned int* __restrict__ merged) {  // [16000][128] words
    __shared__ unsigned int h[8192];   // 1024 bins x 8 words (64 cells nibble)
    int t = threadIdx.x;
    int bk = blockIdx.x;
    int cg = bk >> 4, bc = bk & 15;
    for (int i = t; i < 8192; i += 256) h[i] = 0;
    __syncthreads();
    unsigned int count = gcount[bk];
    if (count > RCAP_CUT) count = RCAP_CUT;
    const unsigned short* e = ent + (size_t)bk * RCAP_CUT;
    for (unsigned int p = t; p < count; p += 256) {
        unsigned int v = e[p];
        unsigned int bin_lo = v & 1023u;
        unsigned int c_lo = v >> 10;
        atomicAdd(&h[bin_lo * 8 + (c_lo >> 3)], 1u << ((c_lo & 7) * 4));
    }
    __syncthreads();
    for (int i = t; i < 8192; i += 256) {
        int bin = bc * 1024 + (i >> 3);
        if (bin < 16000)
            merged[(unsigned)bin * 128u + (unsigned)cg * 8u + (i & 7)] = h[i];
    }
}

// --- 2b. per-bucket frag counts: LDS u16 -> u8 sector-exclusive store ------
__global__ __launch_bounds__(256)
void frag2_kernel(const unsigned int* __restrict__ gcount,
                  const unsigned short* __restrict__ ent,
                  unsigned int* __restrict__ fragw) {   // u8[1000][1024] as u32
    __shared__ unsigned int f[2048];   // 64 g x 32 words (2 u16 cells/word)
    int t = threadIdx.x;
    int bk = blockIdx.x;
    int cg = bk >> 4, gc = bk & 15;
    for (int i = t; i < 2048; i += 256) f[i] = 0;
    __syncthreads();
    unsigned int count = gcount[bk];
    if (count > RCAP_FRAG) count = RCAP_FRAG;
    const unsigned short* e = ent + (size_t)bk * RCAP_FRAG;
    for (unsigned int p = t; p < count; p += 256) {
        unsigned int v = e[p];
        unsigned int g_lo = v & 63u;
        unsigned int c_lo = v >> 6;
        atomicAdd(&f[g_lo * 32 + (c_lo >> 1)], 1u << ((c_lo & 1) * 16));
    }
    __syncthreads();
    for (int i = t; i < 1024; i += 256) {  // 64 g x 16 output words
        int g_lo = i >> 4, wb = i & 15;
        unsigned int lo = f[g_lo * 32 + wb * 2];
        unsigned int hi = f[g_lo * 32 + wb * 2 + 1];
        unsigned int out = (lo & 0xffu) | (((lo >> 16) & 0xffu) << 8)
                         | ((hi & 0xffu) << 16) | (((hi >> 16) & 0xffu) << 24);
        int g = gc * 64 + g_lo;
        if (g < G_)
            fragw[(unsigned)g * 256u + (unsigned)cg * 16u + wb] = out;
    }
}

// --- 3. encoder matmul from merged hist ------------------------------------
__global__ __launch_bounds__(256)
void enc_kernel(const unsigned int* __restrict__ merged, // [16000][128]
                const float* __restrict__ W1,            // [16000][16]
                float* __restrict__ P) {                 // [500][16][1024]
    int t = threadIdx.x;
    int w = t & 127;
    int rl = t >> 7;
    int row0 = blockIdx.x * 32;
    float acc[NHID_][8];
#pragma unroll
    for (int j = 0; j < NHID_; ++j)
#pragma unroll
        for (int u = 0; u < 8; ++u) acc[j][u] = 0.f;
    for (int it = 0; it < 16; ++it) {
        int row = row0 + it * 2 + rl;
        unsigned int mw = merged[(unsigned)row * 128u + (unsigned)w];
        float xv[8];
#pragma unroll
        for (int u = 0; u < 8; ++u)
            xv[u] = __logf((float)(((mw >> (u * 4)) & 0xfu) + 1u));
        const float* wr = W1 + (size_t)row * NHID_;   // wave-uniform -> s_load
#pragma unroll
        for (int j = 0; j < NHID_; ++j) {
            float wj = wr[j];
#pragma unroll
            for (int u = 0; u < 8; ++u) acc[j][u] = fmaf(xv[u], wj, acc[j][u]);
        }
    }
    __shared__ float sp[NHID_][128][8];   // 64 KB
    if (rl == 1) {
#pragma unroll
        for (int j = 0; j < NHID_; ++j)
#pragma unroll
            for (int u = 0; u < 8; ++u) sp[j][w][u] = acc[j][u];
    }
    __syncthreads();
    if (rl == 0) {
        float* Pp = P + (size_t)blockIdx.x * (NHID_ * C_) + (w * 8);
#pragma unroll
        for (int j = 0; j < NHID_; ++j)
#pragma unroll
            for (int u = 0; u < 8; ++u)
                Pp[j * C_ + u] = acc[j][u] + sp[j][w][u];
    }
}

// --- 4. reduce partials -> hT[j][c]; f64 BN sums (32 addrs, 16/addr) -------
__global__ __launch_bounds__(64)
void bn_kernel(const float* __restrict__ P,
               float* __restrict__ hT,
               double* __restrict__ bnsum) {  // [0..15]=sum, [16..31]=sumsq
    int j = blockIdx.x;
    int c = blockIdx.y * 64 + threadIdx.x;
    float s = 0.f;
#pragma unroll 8
    for (int ch = 0; ch < NCHUNK_; ++ch)
        s += P[((size_t)ch * NHID_ + j) * C_ + c];
    hT[j * C_ + c] = s;
    float s1 = s, s2 = s * s;
#pragma unroll
    for (int o = 32; o > 0; o >>= 1) {
        s1 += __shfl_down(s1, o);
        s2 += __shfl_down(s2, o);
    }
    if (threadIdx.x == 0) {
        atomicAdd(&bnsum[j], (double)s1);
        atomicAdd(&bnsum[NHID_ + j], (double)s2);
    }
}

// --- 4b. lw -> bf16 transposed [g][n][64] (k-pad zeroed by memset) ---------
__global__ __launch_bounds__(256)
void lwprep_kernel(const float* __restrict__ lw,      // [1000][50][16]
                   __hip_bfloat16* __restrict__ lwT) { // [1000][16][64]
    int g = blockIdx.x;
    for (int r = threadIdx.x; r < L_ * K_; r += 256) {
        float v = lw[(size_t)g * (L_ * K_) + r];
        lwT[(size_t)g * 1024 + (r & 15) * 64 + (r >> 4)] = __float2bfloat16(v);
    }
}

// --- 5. latent sample + latent KL -> partial store -------------------------
__global__ __launch_bounds__(256)
void latent_kernel(const float* __restrict__ hT,
                   const double* __restrict__ bnsum,
                   const float* __restrict__ gamma,
                   const float* __restrict__ beta,
                   const float* __restrict__ W_loc,   // [16][50]
                   const float* __restrict__ b_loc,
                   const float* __restrict__ W_scale, // [16][50]
                   const float* __restrict__ b_scale,
                   const float* __restrict__ eps,     // [1024][50]
                   float* __restrict__ latT,          // [50][1024]
                   __hip_bfloat16* __restrict__ latbf,// [1024][64] pad 0
                   float* __restrict__ pb) {          // [200]
    int idx = blockIdx.x * 256 + threadIdx.x;
    float kl = 0.f;
    {
        int c = idx / L_;
        int l = idx - c * L_;
        float hb[NHID_];
#pragma unroll
        for (int j = 0; j < NHID_; ++j) {
            float mean = (float)(bnsum[j] * (1.0 / C_));
            float ex2  = (float)(bnsum[NHID_ + j] * (1.0 / C_));
            float var = ex2 - mean * mean;
            float rstd = rsqrtf(var + 1e-5f);
            float sc = gamma[j] * rstd;
            float sh = beta[j] - mean * sc;
            float v = fmaf(hT[j * C_ + c], sc, sh);
            hb[j] = v > 0.f ? v : 0.f;
        }
        float loc = b_loc[l], ls = b_scale[l];
#pragma unroll
        for (int j = 0; j < NHID_; ++j) {
            loc = fmaf(hb[j], W_loc[j * L_ + l], loc);
            ls  = fmaf(hb[j], W_scale[j * L_ + l], ls);
        }
        float qs = 0.1f * __expf(ls);
        float e = eps[idx];
        float lat = fmaf(qs, e, loc);
        latT[(size_t)l * C_ + c] = lat;
        latbf[c * 64 + l] = __float2bfloat16(lat);
        float z = (lat - loc) / qs;
        kl = fmaf(-0.5f * lat, lat, fmaf(0.5f * z, z, __logf(qs)));
    }
    float s = block_sum_256(kl);
    if (threadIdx.x == 0) pb[blockIdx.x] = -CELL_SCALE * s;
}

// --- 6. weight KL (logit_weight + rho_weight), N(0,0.1) -> partial ---------
__global__ __launch_bounds__(256)
void wkl_kernel(const float* __restrict__ lw,
                const float* __restrict__ rw,
                float* __restrict__ pb) {   // [512]
    const int NTOT = G_ * L_ * K_ + G_ * L_;   // 850000
    float s = 0.f;
    for (int i = blockIdx.x * 256 + threadIdx.x; i < NTOT; i += gridDim.x * 256) {
        float w = (i < G_ * L_ * K_) ? lw[i] : rw[i - G_ * L_ * K_];
        s += fmaf(-50.f * w, w, 1.3836465597893733f);
    }
    s = block_sum_256(s);
    if (threadIdx.x == 0) pb[blockIdx.x] = -s;
}

// --- 7a. mixture likelihood via bf16 MFMA -> partial -----------------------
__global__ __launch_bounds__(256)
void mix_kernel(const __hip_bfloat16* __restrict__ latbf, // [1024][64]
                const __hip_bfloat16* __restrict__ lwT,   // [1000][16][64]
                const unsigned int* __restrict__ merged,  // [16000][128]
                const float* __restrict__ baseline,       // [1000][16]
                float* __restrict__ pb) {                 // [4000]
    int g = blockIdx.x;
    int lane = threadIdx.x & 63;
    int wv = threadIdx.x >> 6;
    int n = lane & 15;
    int quad = lane >> 4;
    const __hip_bfloat16* bb = lwT + (size_t)g * 1024 + n * 64 + quad * 8;
    short8 b1 = *(const short8*)bb;
    short8 b2 = *(const short8*)(bb + 32);
    float bl = baseline[g * K_ + n];
    float partial = 0.f;
    int cwave = blockIdx.y * 256 + wv * 64;
#pragma unroll
    for (int mt = 0; mt < 4; ++mt) {
        int c0 = cwave + mt * 16;
        const __hip_bfloat16* aa = latbf + (size_t)(c0 + n) * 64 + quad * 8;
        short8 a1 = *(const short8*)aa;
        short8 a2 = *(const short8*)(aa + 32);
        f32x4 d = {bl, bl, bl, bl};
        d = __builtin_amdgcn_mfma_f32_16x16x32_bf16(a1, b1, d, 0, 0, 0);
        d = __builtin_amdgcn_mfma_f32_16x16x32_bf16(a2, b2, d, 0, 0, 0);
        float mx[4], ex[4];
#pragma unroll
        for (int r = 0; r < 4; ++r) mx[r] = d[r];
#pragma unroll
        for (int m = 1; m < 16; m <<= 1)
#pragma unroll
            for (int r = 0; r < 4; ++r) mx[r] = fmaxf(mx[r], __shfl_xor(mx[r], m));
#pragma unroll
        for (int r = 0; r < 4; ++r) ex[r] = __expf(d[r] - mx[r]);
#pragma unroll
        for (int m = 1; m < 16; m <<= 1)
#pragma unroll
            for (int r = 0; r < 4; ++r) ex[r] += __shfl_xor(ex[r], m);
        int cp = c0 + quad * 4;
        unsigned int hw = merged[(unsigned)(g * K_ + n) * 128u + ((unsigned)cp >> 3)];
        int sb = (cp & 7) * 4;
#pragma unroll
        for (int r = 0; r < 4; ++r) {
            float lse = mx[r] + __logf(ex[r]);
            float cnt = (float)((hw >> (sb + r * 4)) & 0xfu);
            partial = fmaf(cnt, d[r] - lse, partial);
        }
    }
    float s = block_sum_256(-CUT_SCALE * partial);
    if (threadIdx.x == 0) pb[blockIdx.y * G_ + blockIdx.x] = s;
}

// --- 7b. Poisson fragment likelihood -> partial ----------------------------
__global__ __launch_bounds__(256)
void pois_kernel(const float* __restrict__ latT,          // [50][1024]
                 const float* __restrict__ rw,            // [1000][50]
                 const float* __restrict__ rho_bias,
                 const int* __restrict__ libsize,
                 const unsigned char* __restrict__ fragb, // [1000][1024]
                 float* __restrict__ pb) {                // [4000]
    int g = blockIdx.x;
    int c = blockIdx.y * 256 + threadIdx.x;
    const float* rwg = rw + (size_t)g * L_;   // hoists to SGPRs
    float rho = 0.f;
#pragma unroll 10
    for (int l = 0; l < L_; ++l)
        rho = fmaf(latT[l * C_ + c], rwg[l], rho);
    unsigned int fc = fragb[(size_t)g * C_ + c];
    float fe = rho_bias[g] * __expf(rho) * (float)libsize[c];
    float lf = fmaf((float)fc, __logf(fe), -fe) - LGT[fc > 31u ? 31u : fc];
    float s = block_sum_256(-CELL_SCALE * lf);
    if (threadIdx.x == 0) pb[blockIdx.y * G_ + blockIdx.x] = s;
}

// --- 8. finalize: f64-reduce all partials + constant -----------------------
__global__ __launch_bounds__(256)
void final_kernel(const float* __restrict__ pb, float* __restrict__ out) {
    __shared__ double sm[256];
    int t = threadIdx.x;
    double a = 0.0;
    for (int i = t; i < NPB_TOT; i += 256) a += (double)pb[i];
    sm[t] = a;
    __syncthreads();
#pragma unroll
    for (int s = 128; s > 0; s >>= 1) {
        if (t < s) sm[t] += sm[t + s];
        __syncthreads();
    }
    if (t == 0) out[0] = (float)(sm[0] - 138629436.11198905);  // -12.5*4e6*log16
}

extern "C" void kernel_launch(void* const* d_in, const int* in_sizes, int n_in,
                              void* d_out, int out_size, void* d_ws, size_t ws_size,
                              hipStream_t stream) {
    const float* cut_coord = (const float*)d_in[0];
    const float* eps       = (const float*)d_in[1];
    const float* enc_W1    = (const float*)d_in[2];
    // d_in[3] = enc_b1 : cancels through BatchNorm, unused
    const float* bn_gamma  = (const float*)d_in[4];
    const float* bn_beta   = (const float*)d_in[5];
    const float* W_loc     = (const float*)d_in[6];
    const float* b_loc     = (const float*)d_in[7];
    const float* W_scale   = (const float*)d_in[8];
    const float* b_scale   = (const float*)d_in[9];
    const float* logit_w   = (const float*)d_in[10];
    const float* rho_w     = (const float*)d_in[11];
    const float* baseline  = (const float*)d_in[12];
    const float* rho_bias  = (const float*)d_in[13];
    const int* cut_cxg     = (const int*)d_in[14];
    const int* frag_ix     = (const int*)d_in[16];
    const int* libsize     = (const int*)d_in[19];

    int n_cuts  = in_sizes[0];
    int n_frags = in_sizes[16];

    char* ws = (char*)d_ws;
    unsigned int*  gcnt_c  = (unsigned int*)(ws + CTL_OFF);
    unsigned int*  gcnt_f  = (unsigned int*)(ws + CTL_OFF + 1024);
    double*        bnsum   = (double*)(ws + CTL_OFF + 2048);
    __hip_bfloat16* latbf  = (__hip_bfloat16*)(ws + LATBF_OFF);
    __hip_bfloat16* lwT    = (__hip_bfloat16*)(ws + LWT_OFF);
    unsigned short* entc   = (unsigned short*)(ws + ENTC_OFF);
    unsigned short* entf   = (unsigned short*)(ws + ENTF_OFF);
    unsigned int*  merged  = (unsigned int*)(ws + MERGED_OFF);
    unsigned int*  fragw   = (unsigned int*)(ws + FRAGU8_OFF);
    float*         P       = (float*)(ws + P_OFF);
    float*         hT      = (float*)(ws + HT_OFF);
    float*         latT    = (float*)(ws + LATT_OFF);
    float*         pb      = (float*)(ws + PB_OFF);
    float*         out     = (float*)d_out;

    hipMemsetAsync(ws, 0, ZERO_BYTES, stream);

    part_kernel<0><<<(n_cuts + 4095) / 4096, 256, 0, stream>>>(
        cut_cxg, cut_coord, gcnt_c, entc, n_cuts, RCAP_CUT);
    part_kernel<1><<<(n_frags + 4095) / 4096, 256, 0, stream>>>(
        frag_ix, (const float*)nullptr, gcnt_f, entf, n_frags, RCAP_FRAG);
    hist2_kernel<<<256, 256, 0, stream>>>(gcnt_c, entc, merged);
    frag2_kernel<<<256, 256, 0, stream>>>(gcnt_f, entf, fragw);
    lwprep_kernel<<<G_, 256, 0, stream>>>(logit_w, lwT);
    enc_kernel<<<NCHUNK_, 256, 0, stream>>>(merged, enc_W1, P);
    bn_kernel<<<dim3(16, 16), 64, 0, stream>>>(P, hT, bnsum);
    latent_kernel<<<(C_ * L_) / 256, 256, 0, stream>>>(
        hT, bnsum, bn_gamma, bn_beta, W_loc, b_loc, W_scale, b_scale,
        eps, latT, latbf, pb + NPB_MIX + NPB_POIS + NPB_WKL);
    wkl_kernel<<<NPB_WKL, 256, 0, stream>>>(logit_w, rho_w,
                                            pb + NPB_MIX + NPB_POIS);
    mix_kernel<<<dim3(G_, 4), 256, 0, stream>>>(latbf, lwT, merged, baseline, pb);
    pois_kernel<<<dim3(G_, 4), 256, 0, stream>>>(latT, rho_w, rho_bias,
                                                 libsize, (const unsigned char*)fragw,
                                                 pb + NPB_MIX);
    final_kernel<<<1, 256, 0, stream>>>(pb, out);
}

// Round 9
// 294.276 us; speedup vs baseline: 1.3744x; 1.1177x over previous
//
#include <hip/hip_runtime.h>
#include <hip/hip_bf16.h>
#include <math.h>

// ---------------------------------------------------------------------------
// VAE ELBO (chromatin VAE). Sizes fixed by the reference.
//
//  * NB_ENC == NB_DEC == 16, identical binning => ONE nibble histogram serves
//    both the encoder input (log1p counts) and the mixture likelihood.
//  * r3-r5 (3x replicated): global atomics on gfx950 are memory-side ~32B RMW
//    => no per-record global atomics; two-phase LDS counting sort.
//  * r7: same-address atomics serialize ~16ns each => per-block partial
//    stores + one final reduce.
//  * r8 lesson: every kernel < 41us; totals across rounds fit ~13us
//    PER-DISPATCH overhead (rocprof-serialized replay). Fix: 15 -> 8
//    dispatches. Encoder GEMM fused INTO the histogram kernel (counts are
//    already in LDS; W1 rows are wave-uniform s_loads); P shrinks 33->1 MB.
//    frag2/lwprep/wkl ride along as block-ranges. bn loses its atomics.
//  * Mixture logits = bf16 MFMA 16x16x32 (K padded 50->64, pads written by
//    latent/lwprep); softmax over components = shfl_xor across quad-group.
// ---------------------------------------------------------------------------

#define G_      1000
#define C_      1024
#define L_      50
#define K_      16
#define NHID_   16
#define CUT_SCALE   12.5f          // N_TOTAL_CUTS / N_CUTS
#define CELL_SCALE  9.765625f      // N_TOTAL_CELLS / N_CELLS

#define RCAP_CUT  18432            // bucket capacity, cuts  (mean 16000)
#define RCAP_FRAG 9216             // bucket capacity, frags (mean 8000)

// partial buffer: mix[4000] | pois[4000] | wkl[256] | latent[200]
#define NPB_MIX  4000
#define NPB_POIS 4000
#define NPB_WKL  256
#define NPB_LAT  200
#define NPB_TOT  8456

// ws layout (bytes); only [0,2048) (gcnt) is memset per call.
#define GCNTC_OFF  0ull
#define GCNTF_OFF  1024ull
#define ZERO_BYTES 2048ull
#define BNSUM_OFF  2048ull         // f64[32], plain-written by bn
#define LATBF_OFF  2304ull         // bf16 [1024][64], pads written by latent
#define LWT_OFF    133376ull       // bf16 [1000][16][64], pads by lwprep
#define ENTC_OFF   2181376ull      // u16 [256][18432]
#define ENTF_OFF   11618560ull     // u16 [256][9216]
#define MERGED_OFF 16337152ull     // u32 [16000][128] nibble hist
#define FRAGU8_OFF 24529152ull     // u8  [1000][1024]
#define P_OFF      25553152ull     // f32 [16 bc][16 j][1024 c]
#define HT_OFF     26601728ull     // f32 [16][1024]
#define LATT_OFF   26667264ull     // f32 [50][1024]
#define PB_OFF     26872064ull     // f32 [8456]
#define WS_NEED    26905888ull

typedef __attribute__((ext_vector_type(8))) short short8;
typedef __attribute__((ext_vector_type(4))) float f32x4;

__device__ __constant__ float LGT[32] = {   // log(n!)
    0.0f, 0.0f, 0.6931471805599453f, 1.791759469228055f, 3.1780538303479458f,
    4.787491742782046f, 6.579251212010101f, 8.525161361065415f,
    10.60460290274525f, 12.801827480081469f, 15.104412573075516f,
    17.502307845873887f, 19.987214495661885f, 22.552163853123425f,
    25.19122118273868f, 27.89927138384089f, 30.671860106080672f,
    33.50507345013689f, 36.39544520803305f, 39.339884187199495f,
    42.335616460753485f, 45.38013889847691f, 48.47118135183523f,
    51.60667556776438f, 54.78472939811232f, 58.00360522298052f,
    61.261701761002f, 64.55753862700633f, 67.88974313718154f,
    71.25703896716801f, 74.65823634883016f, 78.0922235533153f };

__device__ __forceinline__ float block_sum_256(float v) {
    __shared__ float sm[256];
    int t = threadIdx.x;
    __syncthreads();
    sm[t] = v;
    __syncthreads();
#pragma unroll
    for (int s = 128; s > 0; s >>= 1) {
        if (t < s) sm[t] += sm[t + s];
        __syncthreads();
    }
    return sm[0];
}

// --- 1. radix partition into 256 buckets, cuts AND frags in one grid -------
__global__ __launch_bounds__(256)
void part_kernel(const int* __restrict__ cut_ix,
                 const float* __restrict__ coord,
                 const int* __restrict__ frag_ix,
                 unsigned int* __restrict__ gcnt_c,
                 unsigned int* __restrict__ gcnt_f,
                 unsigned short* __restrict__ entc,
                 unsigned short* __restrict__ entf,
                 int n_cuts, int n_frags, int nblk_cut) {
    __shared__ unsigned int cnt[256], excl[256], cur[256], gbase_s[256];
    __shared__ unsigned short stage[4096];
    __shared__ unsigned char bkof[4096];
    int t = threadIdx.x;
    bool isCut = ((int)blockIdx.x < nblk_cut);
    const int* idx = isCut ? cut_ix : frag_ix;
    int n = isCut ? n_cuts : n_frags;
    int rcap = isCut ? RCAP_CUT : RCAP_FRAG;
    unsigned int* gcount = isCut ? gcnt_c : gcnt_f;
    unsigned short* ent = isCut ? entc : entf;
    int blk = isCut ? blockIdx.x : blockIdx.x - nblk_cut;
    int i0 = blk * 4096;
    unsigned char mybk[16];
    unsigned short myent[16];
    bool myval[16];
    cnt[t] = 0;
    __syncthreads();
#pragma unroll
    for (int k = 0; k < 16; ++k) {
        int i = i0 + k * 256 + t;
        bool v = (i < n);
        unsigned int bk = 0; unsigned short e = 0;
        if (v) {
            int ix = idx[i];
            int c = ix / G_;
            int g = ix - c * G_;
            if (isCut) {
                float x = coord[i];
                int b = (int)(x * 16.0f); b = b > 15 ? 15 : b;
                int bin = g * K_ + b;
                bk = ((unsigned)(c >> 6) << 4) | ((unsigned)bin >> 10);
                e = (unsigned short)(((c & 63) << 10) | (bin & 1023));
            } else {
                bk = ((unsigned)(c >> 6) << 4) | ((unsigned)g >> 6);
                e = (unsigned short)(((c & 63) << 6) | (g & 63));
            }
            atomicAdd(&cnt[bk], 1u);   // LDS atomic
        }
        mybk[k] = (unsigned char)bk; myent[k] = e; myval[k] = v;
    }
    __syncthreads();
    excl[t] = cnt[t];
    __syncthreads();
    for (int o = 1; o < 256; o <<= 1) {
        unsigned int v = (t >= o) ? excl[t - o] : 0u;
        __syncthreads();
        excl[t] += v;
        __syncthreads();
    }
    unsigned int my_excl = excl[t] - cnt[t];
    gbase_s[t] = cnt[t] ? atomicAdd(&gcount[t], cnt[t]) : 0u;  // global reserve
    cur[t] = my_excl;
    __syncthreads();
    excl[t] = my_excl;
    __syncthreads();
#pragma unroll
    for (int k = 0; k < 16; ++k) {
        if (myval[k]) {
            unsigned int p = atomicAdd(&cur[mybk[k]], 1u);   // LDS atomic
            stage[p] = myent[k];
            bkof[p] = mybk[k];
        }
    }
    __syncthreads();
    unsigned int total = excl[255] + cnt[255];
    for (unsigned int p = t; p < total; p += 256) {
        unsigned int bk = bkof[p];
        unsigned int dst = gbase_s[bk] + (p - excl[bk]);
        if (dst < (unsigned)rcap)
            ent[(size_t)bk * rcap + dst] = stage[p];
    }
}

// --- 2. mid kernel: [0,256) hist+enc | [256,512) frag | [512,768) lwprep |
//                    [768,1024) wkl ---------------------------------------
__global__ __launch_bounds__(256)
void mid_kernel(const unsigned int* __restrict__ gcnt_c,
                const unsigned short* __restrict__ entc,
                const unsigned int* __restrict__ gcnt_f,
                const unsigned short* __restrict__ entf,
                const float* __restrict__ W1,        // [16000][16]
                const float* __restrict__ lw,        // [1000][50][16]
                const float* __restrict__ rw,        // [1000][50]
                unsigned int* __restrict__ merged,   // [16000][128]
                unsigned int* __restrict__ fragw,    // u8[1000][1024] as u32
                float* __restrict__ P,               // [16][16][1024]
                __hip_bfloat16* __restrict__ lwT,    // [1000][16][64]
                float* __restrict__ pb_wkl) {        // [256]
    __shared__ unsigned int h[8192];   // 32 KB, shared across roles
    int t = threadIdx.x;
    int bid = blockIdx.x;
    if (bid < 256) {
        // ---- per-bucket cut histogram + encoder partial ----
        int bk = bid, cg = bk >> 4, bc = bk & 15;
        for (int i = t; i < 8192; i += 256) h[i] = 0;
        __syncthreads();
        unsigned int count = gcnt_c[bk];
        if (count > RCAP_CUT) count = RCAP_CUT;
        const unsigned short* e = entc + (size_t)bk * RCAP_CUT;
        for (unsigned int p = t; p < count; p += 256) {
            unsigned int v = e[p];
            unsigned int bin_lo = v & 1023u;
            unsigned int c_lo = v >> 10;
            atomicAdd(&h[bin_lo * 8 + (c_lo >> 3)], 1u << ((c_lo & 7) * 4));
        }
        __syncthreads();
        for (int i = t; i < 8192; i += 256) {
            int bin = bc * 1024 + (i >> 3);
            if (bin < 16000)
                merged[(unsigned)bin * 128u + (unsigned)cg * 8u + (i & 7)] = h[i];
        }
        // encoder partial: quarter q covers 256 bins, thread owns cell c_lo
        int c_lo = t & 63, q = t >> 6;
        float acc[NHID_];
#pragma unroll
        for (int j = 0; j < NHID_; ++j) acc[j] = 0.f;
        int base = bc * 1024 + q * 256;
        int blmax = 16000 - base;
        blmax = blmax < 0 ? 0 : (blmax > 256 ? 256 : blmax);
        int sh = (c_lo & 7) * 4;
        for (int bl = 0; bl < blmax; ++bl) {
            unsigned int w = h[(q * 256 + bl) * 8 + (c_lo >> 3)];
            float xv = __logf((float)(((w >> sh) & 0xfu) + 1u));
            const float* wr = W1 + (size_t)(base + bl) * NHID_;  // s_load
#pragma unroll
            for (int j = 0; j < NHID_; ++j) acc[j] = fmaf(xv, wr[j], acc[j]);
        }
        __syncthreads();
        float* sp = (float*)h;   // [4 q][16 j][64 c] = 16 KB
#pragma unroll
        for (int j = 0; j < NHID_; ++j) sp[q * 1024 + j * 64 + c_lo] = acc[j];
        __syncthreads();
        for (int i = t; i < 1024; i += 256) {
            int j = i >> 6, c = i & 63;
            float v = sp[j * 64 + c] + sp[1024 + j * 64 + c]
                    + sp[2048 + j * 64 + c] + sp[3072 + j * 64 + c];
            P[(size_t)(bc * NHID_ + j) * C_ + cg * 64 + c] = v;
        }
    } else if (bid < 512) {
        // ---- per-bucket frag counts -> u8 ----
        int bk = bid - 256, cg = bk >> 4, gc = bk & 15;
        for (int i = t; i < 2048; i += 256) h[i] = 0;
        __syncthreads();
        unsigned int count = gcnt_f[bk];
        if (count > RCAP_FRAG) count = RCAP_FRAG;
        const unsigned short* e = entf + (size_t)bk * RCAP_FRAG;
        for (unsigned int p = t; p < count; p += 256) {
            unsigned int v = e[p];
            unsigned int g_lo = v & 63u;
            unsigned int c_lo = v >> 6;
            atomicAdd(&h[g_lo * 32 + (c_lo >> 1)], 1u << ((c_lo & 1) * 16));
        }
        __syncthreads();
        for (int i = t; i < 1024; i += 256) {
            int g_lo = i >> 4, wb = i & 15;
            unsigned int lo = h[g_lo * 32 + wb * 2];
            unsigned int hi = h[g_lo * 32 + wb * 2 + 1];
            unsigned int outv = (lo & 0xffu) | (((lo >> 16) & 0xffu) << 8)
                              | ((hi & 0xffu) << 16) | (((hi >> 16) & 0xffu) << 24);
            int g = gc * 64 + g_lo;
            if (g < G_)
                fragw[(unsigned)g * 256u + (unsigned)cg * 16u + wb] = outv;
        }
    } else if (bid < 768) {
        // ---- lwprep: bf16 transpose [g][n][64], k-pads zeroed ----
        for (int g = bid - 512; g < G_; g += 256) {
            for (int r = t; r < L_ * K_; r += 256) {
                float v = lw[(size_t)g * (L_ * K_) + r];
                lwT[(size_t)g * 1024 + (r & 15) * 64 + (r >> 4)] =
                    __float2bfloat16(v);
            }
            for (int i = t; i < 16 * 14; i += 256) {
                int n = i / 14, l = 50 + (i % 14);
                lwT[(size_t)g * 1024 + n * 64 + l] = __float2bfloat16(0.f);
            }
        }
    } else {
        // ---- weight KL ----
        const int NTOT = G_ * L_ * K_ + G_ * L_;   // 850000
        int wb = bid - 768;
        float s = 0.f;
        for (int i = wb * 256 + t; i < NTOT; i += 256 * 256) {
            float w = (i < G_ * L_ * K_) ? lw[i] : rw[i - G_ * L_ * K_];
            s += fmaf(-50.f * w, w, 1.3836465597893733f);
        }
        s = block_sum_256(s);
        if (t == 0) pb_wkl[wb] = -s;
    }
}

// --- 3. bn: reduce P -> hT; write bnsum directly (no atomics) --------------
__global__ __launch_bounds__(256)
void bn_kernel(const float* __restrict__ P,
               float* __restrict__ hT,
               double* __restrict__ bnsum) {
    int j = blockIdx.x;
    int t = threadIdx.x;
    float s1 = 0.f, s2 = 0.f;
#pragma unroll
    for (int u = 0; u < 4; ++u) {
        int c = u * 256 + t;
        float s = 0.f;
#pragma unroll
        for (int bc = 0; bc < 16; ++bc)
            s += P[(size_t)(bc * NHID_ + j) * C_ + c];
        hT[j * C_ + c] = s;
        s1 += s; s2 += s * s;
    }
    s1 = block_sum_256(s1);
    s2 = block_sum_256(s2);
    if (t == 0) { bnsum[j] = (double)s1; bnsum[NHID_ + j] = (double)s2; }
}

// --- 4. latent sample + KL -> partial; writes latT f32 + latbf bf16 + pads -
__global__ __launch_bounds__(256)
void latent_kernel(const float* __restrict__ hT,
                   const double* __restrict__ bnsum,
                   const float* __restrict__ gamma,
                   const float* __restrict__ beta,
                   const float* __restrict__ W_loc,   // [16][50]
                   const float* __restrict__ b_loc,
                   const float* __restrict__ W_scale, // [16][50]
                   const float* __restrict__ b_scale,
                   const float* __restrict__ eps,     // [1024][50]
                   float* __restrict__ latT,          // [50][1024]
                   __hip_bfloat16* __restrict__ latbf,// [1024][64]
                   float* __restrict__ pb) {          // [200]
    int idx = blockIdx.x * 256 + threadIdx.x;
    float kl = 0.f;
    {
        int c = idx / L_;
        int l = idx - c * L_;
        float hb[NHID_];
#pragma unroll
        for (int j = 0; j < NHID_; ++j) {
            float mean = (float)(bnsum[j] * (1.0 / C_));
            float ex2  = (float)(bnsum[NHID_ + j] * (1.0 / C_));
            float var = ex2 - mean * mean;
            float rstd = rsqrtf(var + 1e-5f);
            float sc = gamma[j] * rstd;
            float sh = beta[j] - mean * sc;
            float v = fmaf(hT[j * C_ + c], sc, sh);
            hb[j] = v > 0.f ? v : 0.f;
        }
        float loc = b_loc[l], ls = b_scale[l];
#pragma unroll
        for (int j = 0; j < NHID_; ++j) {
            loc = fmaf(hb[j], W_loc[j * L_ + l], loc);
            ls  = fmaf(hb[j], W_scale[j * L_ + l], ls);
        }
        float qs = 0.1f * __expf(ls);
        float e = eps[idx];
        float lat = fmaf(qs, e, loc);
        latT[(size_t)l * C_ + c] = lat;
        latbf[c * 64 + l] = __float2bfloat16(lat);
        if (l < 14) latbf[c * 64 + 50 + l] = __float2bfloat16(0.f);  // k-pad
        float z = (lat - loc) / qs;
        kl = fmaf(-0.5f * lat, lat, fmaf(0.5f * z, z, __logf(qs)));
    }
    float s = block_sum_256(kl);
    if (threadIdx.x == 0) pb[blockIdx.x] = -CELL_SCALE * s;
}

// --- 5. mixture (bf16 MFMA) + Poisson, one dispatch ------------------------
// grid (1000, 8): y<4 mixture cell-tile y; y>=4 Poisson cell-tile y-4.
__global__ __launch_bounds__(256)
void mixpois_kernel(const __hip_bfloat16* __restrict__ latbf, // [1024][64]
                    const __hip_bfloat16* __restrict__ lwT,   // [1000][16][64]
                    const unsigned int* __restrict__ merged,  // [16000][128]
                    const float* __restrict__ baseline,       // [1000][16]
                    const float* __restrict__ latT,           // [50][1024]
                    const float* __restrict__ rw,             // [1000][50]
                    const float* __restrict__ rho_bias,
                    const int* __restrict__ libsize,
                    const unsigned char* __restrict__ fragb,  // [1000][1024]
                    float* __restrict__ pb) {
    int g = blockIdx.x;
    if (blockIdx.y < 4) {
        int lane = threadIdx.x & 63;
        int wv = threadIdx.x >> 6;
        int n = lane & 15;
        int quad = lane >> 4;
        const __hip_bfloat16* bb = lwT + (size_t)g * 1024 + n * 64 + quad * 8;
        short8 b1 = *(const short8*)bb;
        short8 b2 = *(const short8*)(bb + 32);
        float bl = baseline[g * K_ + n];
        float partial = 0.f;
        int cwave = blockIdx.y * 256 + wv * 64;
#pragma unroll
        for (int mt = 0; mt < 4; ++mt) {
            int c0 = cwave + mt * 16;
            const __hip_bfloat16* aa = latbf + (size_t)(c0 + n) * 64 + quad * 8;
            short8 a1 = *(const short8*)aa;
            short8 a2 = *(const short8*)(aa + 32);
            f32x4 d = {bl, bl, bl, bl};
            d = __builtin_amdgcn_mfma_f32_16x16x32_bf16(a1, b1, d, 0, 0, 0);
            d = __builtin_amdgcn_mfma_f32_16x16x32_bf16(a2, b2, d, 0, 0, 0);
            float mx[4], ex[4];
#pragma unroll
            for (int r = 0; r < 4; ++r) mx[r] = d[r];
#pragma unroll
            for (int m = 1; m < 16; m <<= 1)
#pragma unroll
                for (int r = 0; r < 4; ++r)
                    mx[r] = fmaxf(mx[r], __shfl_xor(mx[r], m));
#pragma unroll
            for (int r = 0; r < 4; ++r) ex[r] = __expf(d[r] - mx[r]);
#pragma unroll
            for (int m = 1; m < 16; m <<= 1)
#pragma unroll
                for (int r = 0; r < 4; ++r) ex[r] += __shfl_xor(ex[r], m);
            int cp = c0 + quad * 4;
            unsigned int hw =
                merged[(unsigned)(g * K_ + n) * 128u + ((unsigned)cp >> 3)];
            int sb = (cp & 7) * 4;
#pragma unroll
            for (int r = 0; r < 4; ++r) {
                float lse = mx[r] + __logf(ex[r]);
                float cnt = (float)((hw >> (sb + r * 4)) & 0xfu);
                partial = fmaf(cnt, d[r] - lse, partial);
            }
        }
        float s = block_sum_256(-CUT_SCALE * partial);
        if (threadIdx.x == 0) pb[blockIdx.y * G_ + g] = s;
    } else {
        int yc = blockIdx.y - 4;
        int c = yc * 256 + threadIdx.x;
        const float* rwg = rw + (size_t)g * L_;   // hoists to SGPRs
        float rho = 0.f;
#pragma unroll 10
        for (int l = 0; l < L_; ++l)
            rho = fmaf(latT[l * C_ + c], rwg[l], rho);
        unsigned int fc = fragb[(size_t)g * C_ + c];
        float fe = rho_bias[g] * __expf(rho) * (float)libsize[c];
        float lf = fmaf((float)fc, __logf(fe), -fe) - LGT[fc > 31u ? 31u : fc];
        float s = block_sum_256(-CELL_SCALE * lf);
        if (threadIdx.x == 0) pb[NPB_MIX + yc * G_ + g] = s;
    }
}

// --- 6. finalize: f64-reduce all partials + constant -----------------------
__global__ __launch_bounds__(256)
void final_kernel(const float* __restrict__ pb, float* __restrict__ out) {
    __shared__ double sm[256];
    int t = threadIdx.x;
    double a = 0.0;
    for (int i = t; i < NPB_TOT; i += 256) a += (double)pb[i];
    sm[t] = a;
    __syncthreads();
#pragma unroll
    for (int s = 128; s > 0; s >>= 1) {
        if (t < s) sm[t] += sm[t + s];
        __syncthreads();
    }
    if (t == 0) out[0] = (float)(sm[0] - 138629436.11198905);  // -12.5*4e6*log16
}

extern "C" void kernel_launch(void* const* d_in, const int* in_sizes, int n_in,
                              void* d_out, int out_size, void* d_ws, size_t ws_size,
                              hipStream_t stream) {
    const float* cut_coord = (const float*)d_in[0];
    const float* eps       = (const float*)d_in[1];
    const float* enc_W1    = (const float*)d_in[2];
    // d_in[3] = enc_b1 : cancels through BatchNorm, unused
    const float* bn_gamma  = (const float*)d_in[4];
    const float* bn_beta   = (const float*)d_in[5];
    const float* W_loc     = (const float*)d_in[6];
    const float* b_loc     = (const float*)d_in[7];
    const float* W_scale   = (const float*)d_in[8];
    const float* b_scale   = (const float*)d_in[9];
    const float* logit_w   = (const float*)d_in[10];
    const float* rho_w     = (const float*)d_in[11];
    const float* baseline  = (const float*)d_in[12];
    const float* rho_bias  = (const float*)d_in[13];
    const int* cut_cxg     = (const int*)d_in[14];
    const int* frag_ix     = (const int*)d_in[16];
    const int* libsize     = (const int*)d_in[19];

    int n_cuts  = in_sizes[0];
    int n_frags = in_sizes[16];

    char* ws = (char*)d_ws;
    unsigned int*   gcnt_c = (unsigned int*)(ws + GCNTC_OFF);
    unsigned int*   gcnt_f = (unsigned int*)(ws + GCNTF_OFF);
    double*         bnsum  = (double*)(ws + BNSUM_OFF);
    __hip_bfloat16* latbf  = (__hip_bfloat16*)(ws + LATBF_OFF);
    __hip_bfloat16* lwT    = (__hip_bfloat16*)(ws + LWT_OFF);
    unsigned short* entc   = (unsigned short*)(ws + ENTC_OFF);
    unsigned short* entf   = (unsigned short*)(ws + ENTF_OFF);
    unsigned int*   merged = (unsigned int*)(ws + MERGED_OFF);
    unsigned int*   fragw  = (unsigned int*)(ws + FRAGU8_OFF);
    float*          P      = (float*)(ws + P_OFF);
    float*          hT     = (float*)(ws + HT_OFF);
    float*          latT   = (float*)(ws + LATT_OFF);
    float*          pb     = (float*)(ws + PB_OFF);
    float*          out    = (float*)d_out;

    int nblk_cut  = (n_cuts + 4095) / 4096;
    int nblk_frag = (n_frags + 4095) / 4096;

    hipMemsetAsync(ws, 0, ZERO_BYTES, stream);   // gcnt only

    part_kernel<<<nblk_cut + nblk_frag, 256, 0, stream>>>(
        cut_cxg, cut_coord, frag_ix, gcnt_c, gcnt_f, entc, entf,
        n_cuts, n_frags, nblk_cut);
    mid_kernel<<<1024, 256, 0, stream>>>(
        gcnt_c, entc, gcnt_f, entf, enc_W1, logit_w, rho_w,
        merged, fragw, P, lwT, pb + NPB_MIX + NPB_POIS);
    bn_kernel<<<NHID_, 256, 0, stream>>>(P, hT, bnsum);
    latent_kernel<<<(C_ * L_) / 256, 256, 0, stream>>>(
        hT, bnsum, bn_gamma, bn_beta, W_loc, b_loc, W_scale, b_scale,
        eps, latT, latbf, pb + NPB_MIX + NPB_POIS + NPB_WKL);
    mixpois_kernel<<<dim3(G_, 8), 256, 0, stream>>>(
        latbf, lwT, merged, baseline, latT, rho_w, rho_bias, libsize,
        (const unsigned char*)fragw, pb);
    final_kernel<<<1, 256, 0, stream>>>(pb, out);
}

// Round 10
// 281.017 us; speedup vs baseline: 1.4392x; 1.0472x over previous
//
#include <hip/hip_runtime.h>
#include <hip/hip_bf16.h>
#include <math.h>

// ---------------------------------------------------------------------------
// VAE ELBO (chromatin VAE). Sizes fixed by the reference.
//
//  * NB_ENC == NB_DEC == 16, identical binning => ONE nibble histogram serves
//    both the encoder input (log1p counts) and the mixture likelihood.
//  * r3-r5 (3x replicated): global atomics on gfx950 are memory-side ~32B RMW
//    => no per-record global atomics; two-phase LDS counting sort.
//  * r7: same-address atomics serialize ~16ns each => per-block partial
//    stores + one final reduce.
//  * r8: ~13us per-dispatch overhead => 8 dispatches total, roles fused as
//    block-ranges of one grid.
//  * r9 lesson: heavy hist+enc role was 256 blocks on 256 CUs -> tail ran at
//    1 wave/SIMD with s_load(W1) latency fully exposed (mid 84us, occ 14%).
//    Fix: 1024 quarter-bucket blocks (256 bins each, 8KB LDS hist, 64-iter
//    enc loop, 16.5KB LDS/block -> 8 blocks/CU) so the tail keeps 4 waves/
//    SIMD and the critical path is 4x shorter. P -> 64 chunks (4MB).
//  * Mixture logits = bf16 MFMA 16x16x32 (K padded 50->64); softmax over
//    components = shfl_xor across quad-group. Poisson uses log(n!) LUT.
// ---------------------------------------------------------------------------

#define G_      1000
#define C_      1024
#define L_      50
#define K_      16
#define NHID_   16
#define CUT_SCALE   12.5f          // N_TOTAL_CUTS / N_CUTS
#define CELL_SCALE  9.765625f      // N_TOTAL_CELLS / N_CELLS

#define RCAP_CUT  18432            // bucket capacity, cuts  (mean 16000)
#define RCAP_FRAG 9216             // bucket capacity, frags (mean 8000)

// partial buffer: mix[4000] | pois[4000] | wkl[256] | latent[200]
#define NPB_MIX  4000
#define NPB_POIS 4000
#define NPB_WKL  256
#define NPB_LAT  200
#define NPB_TOT  8456

// ws layout (bytes); only [0,2048) (gcnt) is memset per call.
#define GCNTC_OFF  0ull
#define GCNTF_OFF  1024ull
#define ZERO_BYTES 2048ull
#define BNSUM_OFF  2048ull         // f64[32], plain-written by bn
#define LATBF_OFF  2304ull         // bf16 [1024][64], pads written by latent
#define LWT_OFF    133376ull       // bf16 [1000][16][64], pads by lwprep
#define ENTC_OFF   2181376ull      // u16 [256][18432]
#define ENTF_OFF   11618560ull     // u16 [256][9216]
#define MERGED_OFF 16337152ull     // u32 [16000][128] nibble hist
#define FRAGU8_OFF 24529152ull     // u8  [1000][1024]
#define P_OFF      25577728ull     // f32 [64 chunk][16 j][1024 c]
#define HT_OFF     29772032ull     // f32 [16][1024]
#define LATT_OFF   29837568ull     // f32 [50][1024]
#define PB_OFF     30042368ull     // f32 [8456]
#define WS_NEED    30076192ull

typedef __attribute__((ext_vector_type(8))) short short8;
typedef __attribute__((ext_vector_type(4))) float f32x4;

__device__ __constant__ float LGT[32] = {   // log(n!)
    0.0f, 0.0f, 0.6931471805599453f, 1.791759469228055f, 3.1780538303479458f,
    4.787491742782046f, 6.579251212010101f, 8.525161361065415f,
    10.60460290274525f, 12.801827480081469f, 15.104412573075516f,
    17.502307845873887f, 19.987214495661885f, 22.552163853123425f,
    25.19122118273868f, 27.89927138384089f, 30.671860106080672f,
    33.50507345013689f, 36.39544520803305f, 39.339884187199495f,
    42.335616460753485f, 45.38013889847691f, 48.47118135183523f,
    51.60667556776438f, 54.78472939811232f, 58.00360522298052f,
    61.261701761002f, 64.55753862700633f, 67.88974313718154f,
    71.25703896716801f, 74.65823634883016f, 78.0922235533153f };

__device__ __forceinline__ float block_sum_256(float v) {
    __shared__ float sm[256];
    int t = threadIdx.x;
    __syncthreads();
    sm[t] = v;
    __syncthreads();
#pragma unroll
    for (int s = 128; s > 0; s >>= 1) {
        if (t < s) sm[t] += sm[t + s];
        __syncthreads();
    }
    return sm[0];
}

// --- 1. radix partition into 256 buckets, cuts AND frags in one grid -------
__global__ __launch_bounds__(256)
void part_kernel(const int* __restrict__ cut_ix,
                 const float* __restrict__ coord,
                 const int* __restrict__ frag_ix,
                 unsigned int* __restrict__ gcnt_c,
                 unsigned int* __restrict__ gcnt_f,
                 unsigned short* __restrict__ entc,
                 unsigned short* __restrict__ entf,
                 int n_cuts, int n_frags, int nblk_cut) {
    __shared__ unsigned int cnt[256], excl[256], cur[256], gbase_s[256];
    __shared__ unsigned short stage[4096];
    __shared__ unsigned char bkof[4096];
    int t = threadIdx.x;
    bool isCut = ((int)blockIdx.x < nblk_cut);
    const int* idx = isCut ? cut_ix : frag_ix;
    int n = isCut ? n_cuts : n_frags;
    int rcap = isCut ? RCAP_CUT : RCAP_FRAG;
    unsigned int* gcount = isCut ? gcnt_c : gcnt_f;
    unsigned short* ent = isCut ? entc : entf;
    int blk = isCut ? blockIdx.x : blockIdx.x - nblk_cut;
    int i0 = blk * 4096;
    unsigned char mybk[16];
    unsigned short myent[16];
    bool myval[16];
    cnt[t] = 0;
    __syncthreads();
#pragma unroll
    for (int k = 0; k < 16; ++k) {
        int i = i0 + k * 256 + t;
        bool v = (i < n);
        unsigned int bk = 0; unsigned short e = 0;
        if (v) {
            int ix = idx[i];
            int c = ix / G_;
            int g = ix - c * G_;
            if (isCut) {
                float x = coord[i];
                int b = (int)(x * 16.0f); b = b > 15 ? 15 : b;
                int bin = g * K_ + b;
                bk = ((unsigned)(c >> 6) << 4) | ((unsigned)bin >> 10);
                e = (unsigned short)(((c & 63) << 10) | (bin & 1023));
            } else {
                bk = ((unsigned)(c >> 6) << 4) | ((unsigned)g >> 6);
                e = (unsigned short)(((c & 63) << 6) | (g & 63));
            }
            atomicAdd(&cnt[bk], 1u);   // LDS atomic
        }
        mybk[k] = (unsigned char)bk; myent[k] = e; myval[k] = v;
    }
    __syncthreads();
    excl[t] = cnt[t];
    __syncthreads();
    for (int o = 1; o < 256; o <<= 1) {
        unsigned int v = (t >= o) ? excl[t - o] : 0u;
        __syncthreads();
        excl[t] += v;
        __syncthreads();
    }
    unsigned int my_excl = excl[t] - cnt[t];
    gbase_s[t] = cnt[t] ? atomicAdd(&gcount[t], cnt[t]) : 0u;  // global reserve
    cur[t] = my_excl;
    __syncthreads();
    excl[t] = my_excl;
    __syncthreads();
#pragma unroll
    for (int k = 0; k < 16; ++k) {
        if (myval[k]) {
            unsigned int p = atomicAdd(&cur[mybk[k]], 1u);   // LDS atomic
            stage[p] = myent[k];
            bkof[p] = mybk[k];
        }
    }
    __syncthreads();
    unsigned int total = excl[255] + cnt[255];
    for (unsigned int p = t; p < total; p += 256) {
        unsigned int bk = bkof[p];
        unsigned int dst = gbase_s[bk] + (p - excl[bk]);
        if (dst < (unsigned)rcap)
            ent[(size_t)bk * rcap + dst] = stage[p];
    }
}

// --- 2. mid kernel: [0,1024) quarter-bucket hist+enc | [1024,1280) frag |
//        [1280,1536) lwprep | [1536,1792) wkl -------------------------------
__global__ __launch_bounds__(256)
void mid_kernel(const unsigned int* __restrict__ gcnt_c,
                const unsigned short* __restrict__ entc,
                const unsigned int* __restrict__ gcnt_f,
                const unsigned short* __restrict__ entf,
                const float* __restrict__ W1,        // [16000][16]
                const float* __restrict__ lw,        // [1000][50][16]
                const float* __restrict__ rw,        // [1000][50]
                unsigned int* __restrict__ merged,   // [16000][128]
                unsigned int* __restrict__ fragw,    // u8[1000][1024] as u32
                float* __restrict__ P,               // [64][16][1024]
                __hip_bfloat16* __restrict__ lwT,    // [1000][16][64]
                float* __restrict__ pb_wkl) {        // [256]
    __shared__ unsigned int h[4096];   // 16 KB, shared across roles
    int t = threadIdx.x;
    int bid = blockIdx.x;
    if (bid < 1024) {
        // ---- quarter-bucket cut histogram + encoder partial ----
        int bk = bid >> 2, q = bid & 3;
        int cg = bk >> 4, bc = bk & 15;
        for (int i = t; i < 2048; i += 256) h[i] = 0;
        __syncthreads();
        unsigned int count = gcnt_c[bk];
        if (count > RCAP_CUT) count = RCAP_CUT;
        const unsigned short* e = entc + (size_t)bk * RCAP_CUT;
        for (unsigned int p = t; p < count; p += 256) {
            unsigned int v = e[p];
            unsigned int bin_lo = v & 1023u;
            if ((int)(bin_lo >> 8) == q) {
                unsigned int c_lo = v >> 10;
                atomicAdd(&h[(bin_lo & 255u) * 8 + (c_lo >> 3)],
                          1u << ((c_lo & 7) * 4));
            }
        }
        __syncthreads();
        for (int i = t; i < 2048; i += 256) {
            int bin = bc * 1024 + q * 256 + (i >> 3);
            if (bin < 16000)
                merged[(unsigned)bin * 128u + (unsigned)cg * 8u + (i & 7)] = h[i];
        }
        // enc: wave `sub` covers 64 bins; thread owns cell c_lo
        int c_lo = t & 63, sub = t >> 6;
        float acc[NHID_];
#pragma unroll
        for (int j = 0; j < NHID_; ++j) acc[j] = 0.f;
        int rbase = bc * 1024 + q * 256 + sub * 64;
        int sh = (c_lo & 7) * 4;
        for (int bl = 0; bl < 64; ++bl) {
            int row = rbase + bl;
            if (row < 16000) {   // wave-uniform (sub is per-wave)
                unsigned int w = h[(sub * 64 + bl) * 8 + (c_lo >> 3)];
                float xv = __logf((float)(((w >> sh) & 0xfu) + 1u));
                const float* wr = W1 + (size_t)row * NHID_;  // s_load
#pragma unroll
                for (int j = 0; j < NHID_; ++j) acc[j] = fmaf(xv, wr[j], acc[j]);
            }
        }
        __syncthreads();
        float* sp = (float*)h;   // [4 sub][16 j][64 c] = 16 KB (reuses hist)
#pragma unroll
        for (int j = 0; j < NHID_; ++j) sp[sub * 1024 + j * 64 + c_lo] = acc[j];
        __syncthreads();
        for (int i = t; i < 1024; i += 256) {
            int j = i >> 6, c = i & 63;
            float v = sp[j * 64 + c] + sp[1024 + j * 64 + c]
                    + sp[2048 + j * 64 + c] + sp[3072 + j * 64 + c];
            P[(size_t)((bc * 4 + q) * NHID_ + j) * C_ + cg * 64 + c] = v;
        }
    } else if (bid < 1280) {
        // ---- per-bucket frag counts -> u8 ----
        int bk = bid - 1024, cg = bk >> 4, gc = bk & 15;
        for (int i = t; i < 2048; i += 256) h[i] = 0;
        __syncthreads();
        unsigned int count = gcnt_f[bk];
        if (count > RCAP_FRAG) count = RCAP_FRAG;
        const unsigned short* e = entf + (size_t)bk * RCAP_FRAG;
        for (unsigned int p = t; p < count; p += 256) {
            unsigned int v = e[p];
            unsigned int g_lo = v & 63u;
            unsigned int c_lo = v >> 6;
            atomicAdd(&h[g_lo * 32 + (c_lo >> 1)], 1u << ((c_lo & 1) * 16));
        }
        __syncthreads();
        for (int i = t; i < 1024; i += 256) {
            int g_lo = i >> 4, wb = i & 15;
            unsigned int lo = h[g_lo * 32 + wb * 2];
            unsigned int hi = h[g_lo * 32 + wb * 2 + 1];
            unsigned int outv = (lo & 0xffu) | (((lo >> 16) & 0xffu) << 8)
                              | ((hi & 0xffu) << 16) | (((hi >> 16) & 0xffu) << 24);
            int g = gc * 64 + g_lo;
            if (g < G_)
                fragw[(unsigned)g * 256u + (unsigned)cg * 16u + wb] = outv;
        }
    } else if (bid < 1536) {
        // ---- lwprep: bf16 transpose [g][n][64], k-pads zeroed ----
        for (int g = bid - 1280; g < G_; g += 256) {
            for (int r = t; r < L_ * K_; r += 256) {
                float v = lw[(size_t)g * (L_ * K_) + r];
                lwT[(size_t)g * 1024 + (r & 15) * 64 + (r >> 4)] =
                    __float2bfloat16(v);
            }
            for (int i = t; i < 16 * 14; i += 256) {
                int n = i / 14, l = 50 + (i % 14);
                lwT[(size_t)g * 1024 + n * 64 + l] = __float2bfloat16(0.f);
            }
        }
    } else {
        // ---- weight KL ----
        const int NTOT = G_ * L_ * K_ + G_ * L_;   // 850000
        int wb = bid - 1536;
        float s = 0.f;
        for (int i = wb * 256 + t; i < NTOT; i += 256 * 256) {
            float w = (i < G_ * L_ * K_) ? lw[i] : rw[i - G_ * L_ * K_];
            s += fmaf(-50.f * w, w, 1.3836465597893733f);
        }
        s = block_sum_256(s);
        if (t == 0) pb_wkl[wb] = -s;
    }
}

// --- 3. bn: reduce P (64 chunks) -> hT; write bnsum directly ---------------
__global__ __launch_bounds__(256)
void bn_kernel(const float* __restrict__ P,
               float* __restrict__ hT,
               double* __restrict__ bnsum) {
    int j = blockIdx.x;
    int t = threadIdx.x;
    float s1 = 0.f, s2 = 0.f;
#pragma unroll
    for (int u = 0; u < 4; ++u) {
        int c = u * 256 + t;
        float s = 0.f;
#pragma unroll 8
        for (int ch = 0; ch < 64; ++ch)
            s += P[(size_t)(ch * NHID_ + j) * C_ + c];
        hT[j * C_ + c] = s;
        s1 += s; s2 += s * s;
    }
    s1 = block_sum_256(s1);
    s2 = block_sum_256(s2);
    if (t == 0) { bnsum[j] = (double)s1; bnsum[NHID_ + j] = (double)s2; }
}

// --- 4. latent sample + KL -> partial; writes latT f32 + latbf bf16 + pads -
__global__ __launch_bounds__(256)
void latent_kernel(const float* __restrict__ hT,
                   const double* __restrict__ bnsum,
                   const float* __restrict__ gamma,
                   const float* __restrict__ beta,
                   const float* __restrict__ W_loc,   // [16][50]
                   const float* __restrict__ b_loc,
                   const float* __restrict__ W_scale, // [16][50]
                   const float* __restrict__ b_scale,
                   const float* __restrict__ eps,     // [1024][50]
                   float* __restrict__ latT,          // [50][1024]
                   __hip_bfloat16* __restrict__ latbf,// [1024][64]
                   float* __restrict__ pb) {          // [200]
    int idx = blockIdx.x * 256 + threadIdx.x;
    float kl = 0.f;
    {
        int c = idx / L_;
        int l = idx - c * L_;
        float hb[NHID_];
#pragma unroll
        for (int j = 0; j < NHID_; ++j) {
            float mean = (float)(bnsum[j] * (1.0 / C_));
            float ex2  = (float)(bnsum[NHID_ + j] * (1.0 / C_));
            float var = ex2 - mean * mean;
            float rstd = rsqrtf(var + 1e-5f);
            float sc = gamma[j] * rstd;
            float sh = beta[j] - mean * sc;
            float v = fmaf(hT[j * C_ + c], sc, sh);
            hb[j] = v > 0.f ? v : 0.f;
        }
        float loc = b_loc[l], ls = b_scale[l];
#pragma unroll
        for (int j = 0; j < NHID_; ++j) {
            loc = fmaf(hb[j], W_loc[j * L_ + l], loc);
            ls  = fmaf(hb[j], W_scale[j * L_ + l], ls);
        }
        float qs = 0.1f * __expf(ls);
        float e = eps[idx];
        float lat = fmaf(qs, e, loc);
        latT[(size_t)l * C_ + c] = lat;
        latbf[c * 64 + l] = __float2bfloat16(lat);
        if (l < 14) latbf[c * 64 + 50 + l] = __float2bfloat16(0.f);  // k-pad
        float z = (lat - loc) / qs;
        kl = fmaf(-0.5f * lat, lat, fmaf(0.5f * z, z, __logf(qs)));
    }
    float s = block_sum_256(kl);
    if (threadIdx.x == 0) pb[blockIdx.x] = -CELL_SCALE * s;
}

// --- 5. mixture (bf16 MFMA) + Poisson, one dispatch ------------------------
// grid (1000, 8): y<4 mixture cell-tile y; y>=4 Poisson cell-tile y-4.
__global__ __launch_bounds__(256)
void mixpois_kernel(const __hip_bfloat16* __restrict__ latbf, // [1024][64]
                    const __hip_bfloat16* __restrict__ lwT,   // [1000][16][64]
                    const unsigned int* __restrict__ merged,  // [16000][128]
                    const float* __restrict__ baseline,       // [1000][16]
                    const float* __restrict__ latT,           // [50][1024]
                    const float* __restrict__ rw,             // [1000][50]
                    const float* __restrict__ rho_bias,
                    const int* __restrict__ libsize,
                    const unsigned char* __restrict__ fragb,  // [1000][1024]
                    float* __restrict__ pb) {
    int g = blockIdx.x;
    if (blockIdx.y < 4) {
        int lane = threadIdx.x & 63;
        int wv = threadIdx.x >> 6;
        int n = lane & 15;
        int quad = lane >> 4;
        const __hip_bfloat16* bb = lwT + (size_t)g * 1024 + n * 64 + quad * 8;
        short8 b1 = *(const short8*)bb;
        short8 b2 = *(const short8*)(bb + 32);
        float bl = baseline[g * K_ + n];
        float partial = 0.f;
        int cwave = blockIdx.y * 256 + wv * 64;
#pragma unroll
        for (int mt = 0; mt < 4; ++mt) {
            int c0 = cwave + mt * 16;
            const __hip_bfloat16* aa = latbf + (size_t)(c0 + n) * 64 + quad * 8;
            short8 a1 = *(const short8*)aa;
            short8 a2 = *(const short8*)(aa + 32);
            f32x4 d = {bl, bl, bl, bl};
            d = __builtin_amdgcn_mfma_f32_16x16x32_bf16(a1, b1, d, 0, 0, 0);
            d = __builtin_amdgcn_mfma_f32_16x16x32_bf16(a2, b2, d, 0, 0, 0);
            float mx[4], ex[4];
#pragma unroll
            for (int r = 0; r < 4; ++r) mx[r] = d[r];
#pragma unroll
            for (int m = 1; m < 16; m <<= 1)
#pragma unroll
                for (int r = 0; r < 4; ++r)
                    mx[r] = fmaxf(mx[r], __shfl_xor(mx[r], m));
#pragma unroll
            for (int r = 0; r < 4; ++r) ex[r] = __expf(d[r] - mx[r]);
#pragma unroll
            for (int m = 1; m < 16; m <<= 1)
#pragma unroll
                for (int r = 0; r < 4; ++r) ex[r] += __shfl_xor(ex[r], m);
            int cp = c0 + quad * 4;
            unsigned int hw =
                merged[(unsigned)(g * K_ + n) * 128u + ((unsigned)cp >> 3)];
            int sb = (cp & 7) * 4;
#pragma unroll
            for (int r = 0; r < 4; ++r) {
                float lse = mx[r] + __logf(ex[r]);
                float cnt = (float)((hw >> (sb + r * 4)) & 0xfu);
                partial = fmaf(cnt, d[r] - lse, partial);
            }
        }
        float s = block_sum_256(-CUT_SCALE * partial);
        if (threadIdx.x == 0) pb[blockIdx.y * G_ + g] = s;
    } else {
        int yc = blockIdx.y - 4;
        int c = yc * 256 + threadIdx.x;
        const float* rwg = rw + (size_t)g * L_;   // hoists to SGPRs
        float rho = 0.f;
#pragma unroll 10
        for (int l = 0; l < L_; ++l)
            rho = fmaf(latT[l * C_ + c], rwg[l], rho);
        unsigned int fc = fragb[(size_t)g * C_ + c];
        float fe = rho_bias[g] * __expf(rho) * (float)libsize[c];
        float lf = fmaf((float)fc, __logf(fe), -fe) - LGT[fc > 31u ? 31u : fc];
        float s = block_sum_256(-CELL_SCALE * lf);
        if (threadIdx.x == 0) pb[NPB_MIX + yc * G_ + g] = s;
    }
}

// --- 6. finalize: f64-reduce all partials + constant -----------------------
__global__ __launch_bounds__(256)
void final_kernel(const float* __restrict__ pb, float* __restrict__ out) {
    __shared__ double sm[256];
    int t = threadIdx.x;
    double a = 0.0;
    for (int i = t; i < NPB_TOT; i += 256) a += (double)pb[i];
    sm[t] = a;
    __syncthreads();
#pragma unroll
    for (int s = 128; s > 0; s >>= 1) {
        if (t < s) sm[t] += sm[t + s];
        __syncthreads();
    }
    if (t == 0) out[0] = (float)(sm[0] - 138629436.11198905);  // -12.5*4e6*log16
}

extern "C" void kernel_launch(void* const* d_in, const int* in_sizes, int n_in,
                              void* d_out, int out_size, void* d_ws, size_t ws_size,
                              hipStream_t stream) {
    const float* cut_coord = (const float*)d_in[0];
    const float* eps       = (const float*)d_in[1];
    const float* enc_W1    = (const float*)d_in[2];
    // d_in[3] = enc_b1 : cancels through BatchNorm, unused
    const float* bn_gamma  = (const float*)d_in[4];
    const float* bn_beta   = (const float*)d_in[5];
    const float* W_loc     = (const float*)d_in[6];
    const float* b_loc     = (const float*)d_in[7];
    const float* W_scale   = (const float*)d_in[8];
    const float* b_scale   = (const float*)d_in[9];
    const float* logit_w   = (const float*)d_in[10];
    const float* rho_w     = (const float*)d_in[11];
    const float* baseline  = (const float*)d_in[12];
    const float* rho_bias  = (const float*)d_in[13];
    const int* cut_cxg     = (const int*)d_in[14];
    const int* frag_ix     = (const int*)d_in[16];
    const int* libsize     = (const int*)d_in[19];

    int n_cuts  = in_sizes[0];
    int n_frags = in_sizes[16];

    char* ws = (char*)d_ws;
    unsigned int*   gcnt_c = (unsigned int*)(ws + GCNTC_OFF);
    unsigned int*   gcnt_f = (unsigned int*)(ws + GCNTF_OFF);
    double*         bnsum  = (double*)(ws + BNSUM_OFF);
    __hip_bfloat16* latbf  = (__hip_bfloat16*)(ws + LATBF_OFF);
    __hip_bfloat16* lwT    = (__hip_bfloat16*)(ws + LWT_OFF);
    unsigned short* entc   = (unsigned short*)(ws + ENTC_OFF);
    unsigned short* entf   = (unsigned short*)(ws + ENTF_OFF);
    unsigned int*   merged = (unsigned int*)(ws + MERGED_OFF);
    unsigned int*   fragw  = (unsigned int*)(ws + FRAGU8_OFF);
    float*          P      = (float*)(ws + P_OFF);
    float*          hT     = (float*)(ws + HT_OFF);
    float*          latT   = (float*)(ws + LATT_OFF);
    float*          pb     = (float*)(ws + PB_OFF);
    float*          out    = (float*)d_out;

    int nblk_cut  = (n_cuts + 4095) / 4096;
    int nblk_frag = (n_frags + 4095) / 4096;

    hipMemsetAsync(ws, 0, ZERO_BYTES, stream);   // gcnt only

    part_kernel<<<nblk_cut + nblk_frag, 256, 0, stream>>>(
        cut_cxg, cut_coord, frag_ix, gcnt_c, gcnt_f, entc, entf,
        n_cuts, n_frags, nblk_cut);
    mid_kernel<<<1792, 256, 0, stream>>>(
        gcnt_c, entc, gcnt_f, entf, enc_W1, logit_w, rho_w,
        merged, fragw, P, lwT, pb + NPB_MIX + NPB_POIS);
    bn_kernel<<<NHID_, 256, 0, stream>>>(P, hT, bnsum);
    latent_kernel<<<(C_ * L_) / 256, 256, 0, stream>>>(
        hT, bnsum, bn_gamma, bn_beta, W_loc, b_loc, W_scale, b_scale,
        eps, latT, latbf, pb + NPB_MIX + NPB_POIS + NPB_WKL);
    mixpois_kernel<<<dim3(G_, 8), 256, 0, stream>>>(
        latbf, lwT, merged, baseline, latT, rho_w, rho_bias, libsize,
        (const unsigned char*)fragw, pb);
    final_kernel<<<1, 256, 0, stream>>>(pb, out);
}

// Round 11
// 276.243 us; speedup vs baseline: 1.4641x; 1.0173x over previous
//
#include <hip/hip_runtime.h>
#include <hip/hip_bf16.h>
#include <math.h>

// ---------------------------------------------------------------------------
// VAE ELBO (chromatin VAE). Sizes fixed by the reference.
//
//  * NB_ENC == NB_DEC == 16, identical binning => ONE nibble histogram serves
//    both the encoder input (log1p counts) and the mixture likelihood.
//  * r3-r5 (3x replicated): global atomics on gfx950 are memory-side ~32B RMW
//    => no per-record global atomics; two-phase LDS counting sort.
//  * r7: same-address atomics serialize ~16ns each => per-block partial
//    stores + one final reduce.
//  * r8: per-dispatch overhead matters => roles fused as block-ranges.
//  * r9/r10: heavy role needs BOTH block-level parallelism (1024 quarter-
//    bucket blocks) AND per-iteration latency hiding. r10 still stalled 73%
//    on one-load-per-iter scan + s_load(W1) per enc iter. Fix: W1 staged in
//    LDS (broadcast reads, load issued under the scan), scan reads u32 entry
//    pairs hand-batched 4-wide (8 loads in flight).
//  * part: 8192 rec/block, two-pass (count, re-read+scatter) => half the
//    blocks, half the reserve-atomic chains.
//  * Mixture logits = bf16 MFMA 16x16x32 (K padded 50->64); softmax over
//    components = shfl_xor across quad-group. Poisson uses log(n!) LUT.
// ---------------------------------------------------------------------------

#define G_      1000
#define C_      1024
#define L_      50
#define K_      16
#define NHID_   16
#define CUT_SCALE   12.5f          // N_TOTAL_CUTS / N_CUTS
#define CELL_SCALE  9.765625f      // N_TOTAL_CELLS / N_CELLS

#define RCAP_CUT  18432            // bucket capacity, cuts  (mean 16000)
#define RCAP_FRAG 9216             // bucket capacity, frags (mean 8000)

// partial buffer: mix[4000] | pois[4000] | wkl[256] | latent[200]
#define NPB_MIX  4000
#define NPB_POIS 4000
#define NPB_WKL  256
#define NPB_LAT  200
#define NPB_TOT  8456

// ws layout (bytes); only [0,2048) (gcnt) is memset per call.
#define GCNTC_OFF  0ull
#define GCNTF_OFF  1024ull
#define ZERO_BYTES 2048ull
#define BNSUM_OFF  2048ull         // f64[32], plain-written by bn
#define LATBF_OFF  2304ull         // bf16 [1024][64], pads written by latent
#define LWT_OFF    133376ull       // bf16 [1000][16][64], pads by lwprep
#define ENTC_OFF   2181376ull      // u16 [256][18432]
#define ENTF_OFF   11618560ull     // u16 [256][9216]
#define MERGED_OFF 16337152ull     // u32 [16000][128] nibble hist
#define FRAGU8_OFF 24529152ull     // u8  [1000][1024]
#define P_OFF      25577728ull     // f32 [64 chunk][16 j][1024 c]
#define HT_OFF     29772032ull     // f32 [16][1024]
#define LATT_OFF   29837568ull     // f32 [50][1024]
#define PB_OFF     30042368ull     // f32 [8456]
#define WS_NEED    30076192ull

typedef __attribute__((ext_vector_type(8))) short short8;
typedef __attribute__((ext_vector_type(4))) float f32x4;

__device__ __constant__ float LGT[32] = {   // log(n!)
    0.0f, 0.0f, 0.6931471805599453f, 1.791759469228055f, 3.1780538303479458f,
    4.787491742782046f, 6.579251212010101f, 8.525161361065415f,
    10.60460290274525f, 12.801827480081469f, 15.104412573075516f,
    17.502307845873887f, 19.987214495661885f, 22.552163853123425f,
    25.19122118273868f, 27.89927138384089f, 30.671860106080672f,
    33.50507345013689f, 36.39544520803305f, 39.339884187199495f,
    42.335616460753485f, 45.38013889847691f, 48.47118135183523f,
    51.60667556776438f, 54.78472939811232f, 58.00360522298052f,
    61.261701761002f, 64.55753862700633f, 67.88974313718154f,
    71.25703896716801f, 74.65823634883016f, 78.0922235533153f };

__device__ __forceinline__ float block_sum_256(float v) {
    __shared__ float sm[256];
    int t = threadIdx.x;
    __syncthreads();
    sm[t] = v;
    __syncthreads();
#pragma unroll
    for (int s = 128; s > 0; s >>= 1) {
        if (t < s) sm[t] += sm[t + s];
        __syncthreads();
    }
    return sm[0];
}

// --- 1. radix partition into 256 buckets; 8192 records/block, two-pass -----
__global__ __launch_bounds__(256)
void part_kernel(const int* __restrict__ cut_ix,
                 const float* __restrict__ coord,
                 const int* __restrict__ frag_ix,
                 unsigned int* __restrict__ gcnt_c,
                 unsigned int* __restrict__ gcnt_f,
                 unsigned short* __restrict__ entc,
                 unsigned short* __restrict__ entf,
                 int n_cuts, int n_frags, int nblk_cut) {
    __shared__ unsigned int cnt[256], excl[256], cur[256], gbase_s[256];
    __shared__ unsigned short stage[8192];
    __shared__ unsigned char bkof[8192];
    int t = threadIdx.x;
    bool isCut = ((int)blockIdx.x < nblk_cut);
    const int* idx = isCut ? cut_ix : frag_ix;
    int n = isCut ? n_cuts : n_frags;
    int rcap = isCut ? RCAP_CUT : RCAP_FRAG;
    unsigned int* gcount = isCut ? gcnt_c : gcnt_f;
    unsigned short* ent = isCut ? entc : entf;
    int blk = isCut ? blockIdx.x : blockIdx.x - nblk_cut;
    int i0 = blk * 8192;
    cnt[t] = 0;
    __syncthreads();
    // pass A: count
#pragma unroll 4
    for (int k = 0; k < 32; ++k) {
        int i = i0 + k * 256 + t;
        if (i < n) {
            int ix = idx[i];
            int c = ix / G_;
            int g = ix - c * G_;
            unsigned int bk;
            if (isCut) {
                float x = coord[i];
                int b = (int)(x * 16.0f); b = b > 15 ? 15 : b;
                bk = ((unsigned)(c >> 6) << 4) | ((unsigned)(g * K_ + b) >> 10);
            } else {
                bk = ((unsigned)(c >> 6) << 4) | ((unsigned)g >> 6);
            }
            atomicAdd(&cnt[bk], 1u);   // LDS atomic
        }
    }
    __syncthreads();
    excl[t] = cnt[t];
    __syncthreads();
    for (int o = 1; o < 256; o <<= 1) {
        unsigned int v = (t >= o) ? excl[t - o] : 0u;
        __syncthreads();
        excl[t] += v;
        __syncthreads();
    }
    unsigned int my_excl = excl[t] - cnt[t];
    gbase_s[t] = cnt[t] ? atomicAdd(&gcount[t], cnt[t]) : 0u;  // global reserve
    cur[t] = my_excl;
    __syncthreads();
    excl[t] = my_excl;
    __syncthreads();
    // pass B: re-read, compute entry, scatter into LDS stage
#pragma unroll 4
    for (int k = 0; k < 32; ++k) {
        int i = i0 + k * 256 + t;
        if (i < n) {
            int ix = idx[i];
            int c = ix / G_;
            int g = ix - c * G_;
            unsigned int bk; unsigned short e;
            if (isCut) {
                float x = coord[i];
                int b = (int)(x * 16.0f); b = b > 15 ? 15 : b;
                int bin = g * K_ + b;
                bk = ((unsigned)(c >> 6) << 4) | ((unsigned)bin >> 10);
                e = (unsigned short)(((c & 63) << 10) | (bin & 1023));
            } else {
                bk = ((unsigned)(c >> 6) << 4) | ((unsigned)g >> 6);
                e = (unsigned short)(((c & 63) << 6) | (g & 63));
            }
            unsigned int p = atomicAdd(&cur[bk], 1u);   // LDS atomic
            stage[p] = e;
            bkof[p] = (unsigned char)bk;
        }
    }
    __syncthreads();
    int total_here = (i0 + 8192 <= n) ? 8192 : (n - i0 > 0 ? n - i0 : 0);
    for (int p = t; p < total_here; p += 256) {
        unsigned int bk = bkof[p];
        unsigned int dst = gbase_s[bk] + (p - excl[bk]);
        if (dst < (unsigned)rcap)
            ent[(size_t)bk * rcap + dst] = stage[p];
    }
}

// --- 2. mid kernel: [0,1024) quarter-bucket hist+enc | [1024,1280) frag |
//        [1280,1536) lwprep | [1536,1792) wkl -------------------------------
__global__ __launch_bounds__(256)
void mid_kernel(const unsigned int* __restrict__ gcnt_c,
                const unsigned short* __restrict__ entc,
                const unsigned int* __restrict__ gcnt_f,
                const unsigned short* __restrict__ entf,
                const float* __restrict__ W1,        // [16000][16]
                const float* __restrict__ lw,        // [1000][50][16]
                const float* __restrict__ rw,        // [1000][50]
                unsigned int* __restrict__ merged,   // [16000][128]
                unsigned int* __restrict__ fragw,    // u8[1000][1024] as u32
                float* __restrict__ P,               // [64][16][1024]
                __hip_bfloat16* __restrict__ lwT,    // [1000][16][64]
                float* __restrict__ pb_wkl) {        // [256]
    __shared__ unsigned int h[4096];   // 16 KB: hist in [0,2048), sp aliases all
    __shared__ float w1s[4096];        // 16 KB: 256 W1 rows x 16
    int t = threadIdx.x;
    int bid = blockIdx.x;
    if (bid < 1024) {
        // ---- quarter-bucket cut histogram + encoder partial ----
        int bk = bid >> 2, q = bid & 3;
        int cg = bk >> 4, bc = bk & 15;
        // stage W1 window (no dependency; latency hides under scan)
        int wbase = (bc * 1024 + q * 256) * NHID_;   // float index
#pragma unroll
        for (int r = 0; r < 16; ++r) {
            int i = r * 256 + t;
            int gi = wbase + i;
            w1s[i] = (gi < 16000 * NHID_) ? W1[gi] : 0.f;
        }
        for (int i = t; i < 2048; i += 256) h[i] = 0;
        __syncthreads();
        unsigned int count = gcnt_c[bk];
        if (count > RCAP_CUT) count = RCAP_CUT;
        const unsigned int* e32 = (const unsigned int*)(entc + (size_t)bk * RCAP_CUT);
        unsigned int npair = count >> 1;
        for (unsigned int base = 0; base < npair; base += 1024) {
            unsigned int w[4]; bool val[4];
#pragma unroll
            for (int u = 0; u < 4; ++u) {
                unsigned int p = base + u * 256 + t;
                val[u] = (p < npair);
                w[u] = val[u] ? e32[p] : 0u;
            }
#pragma unroll
            for (int u = 0; u < 4; ++u) {
                if (val[u]) {
                    unsigned int v0 = w[u] & 0xffffu, v1 = w[u] >> 16;
                    unsigned int b0 = v0 & 1023u, b1 = v1 & 1023u;
                    if ((int)(b0 >> 8) == q) {
                        unsigned int c0 = v0 >> 10;
                        atomicAdd(&h[(b0 & 255u) * 8 + (c0 >> 3)],
                                  1u << ((c0 & 7) * 4));
                    }
                    if ((int)(b1 >> 8) == q) {
                        unsigned int c1 = v1 >> 10;
                        atomicAdd(&h[(b1 & 255u) * 8 + (c1 >> 3)],
                                  1u << ((c1 & 7) * 4));
                    }
                }
            }
        }
        if (t == 0 && (count & 1u)) {
            unsigned int v = ((const unsigned short*)e32)[count - 1];
            unsigned int b0 = v & 1023u;
            if ((int)(b0 >> 8) == q) {
                unsigned int c0 = v >> 10;
                atomicAdd(&h[(b0 & 255u) * 8 + (c0 >> 3)], 1u << ((c0 & 7) * 4));
            }
        }
        __syncthreads();
        for (int i = t; i < 2048; i += 256) {
            int bin = bc * 1024 + q * 256 + (i >> 3);
            if (bin < 16000)
                merged[(unsigned)bin * 128u + (unsigned)cg * 8u + (i & 7)] = h[i];
        }
        // enc: wave `sub` covers 64 bins; thread owns cell c_lo; W1 from LDS
        int c_lo = t & 63, sub = t >> 6;
        float acc[NHID_];
#pragma unroll
        for (int j = 0; j < NHID_; ++j) acc[j] = 0.f;
        int rbase = bc * 1024 + q * 256 + sub * 64;
        int sh = (c_lo & 7) * 4;
        const float4* w1v = (const float4*)w1s;
#pragma unroll 2
        for (int bl = 0; bl < 64; ++bl) {
            int row = rbase + bl;
            if (row < 16000) {   // wave-uniform
                int rl = sub * 64 + bl;
                unsigned int w = h[rl * 8 + (c_lo >> 3)];
                float xv = __logf((float)(((w >> sh) & 0xfu) + 1u));
                float4 wa = w1v[rl * 4 + 0];   // LDS broadcast
                float4 wb = w1v[rl * 4 + 1];
                float4 wc = w1v[rl * 4 + 2];
                float4 wd = w1v[rl * 4 + 3];
                acc[0] = fmaf(xv, wa.x, acc[0]);  acc[1] = fmaf(xv, wa.y, acc[1]);
                acc[2] = fmaf(xv, wa.z, acc[2]);  acc[3] = fmaf(xv, wa.w, acc[3]);
                acc[4] = fmaf(xv, wb.x, acc[4]);  acc[5] = fmaf(xv, wb.y, acc[5]);
                acc[6] = fmaf(xv, wb.z, acc[6]);  acc[7] = fmaf(xv, wb.w, acc[7]);
                acc[8] = fmaf(xv, wc.x, acc[8]);  acc[9] = fmaf(xv, wc.y, acc[9]);
                acc[10] = fmaf(xv, wc.z, acc[10]); acc[11] = fmaf(xv, wc.w, acc[11]);
                acc[12] = fmaf(xv, wd.x, acc[12]); acc[13] = fmaf(xv, wd.y, acc[13]);
                acc[14] = fmaf(xv, wd.z, acc[14]); acc[15] = fmaf(xv, wd.w, acc[15]);
            }
        }
        __syncthreads();
        float* sp = (float*)h;   // full 16 KB, hist dead now
#pragma unroll
        for (int j = 0; j < NHID_; ++j) sp[sub * 1024 + j * 64 + c_lo] = acc[j];
        __syncthreads();
        for (int i = t; i < 1024; i += 256) {
            int j = i >> 6, c = i & 63;
            float v = sp[j * 64 + c] + sp[1024 + j * 64 + c]
                    + sp[2048 + j * 64 + c] + sp[3072 + j * 64 + c];
            P[(size_t)((bc * 4 + q) * NHID_ + j) * C_ + cg * 64 + c] = v;
        }
    } else if (bid < 1280) {
        // ---- per-bucket frag counts -> u8 ----
        int bk = bid - 1024, cg = bk >> 4, gc = bk & 15;
        for (int i = t; i < 2048; i += 256) h[i] = 0;
        __syncthreads();
        unsigned int count = gcnt_f[bk];
        if (count > RCAP_FRAG) count = RCAP_FRAG;
        const unsigned short* e = entf + (size_t)bk * RCAP_FRAG;
#pragma unroll 4
        for (unsigned int p = t; p < count; p += 256) {
            unsigned int v = e[p];
            unsigned int g_lo = v & 63u;
            unsigned int c_lo = v >> 6;
            atomicAdd(&h[g_lo * 32 + (c_lo >> 1)], 1u << ((c_lo & 1) * 16));
        }
        __syncthreads();
        for (int i = t; i < 1024; i += 256) {
            int g_lo = i >> 4, wb = i & 15;
            unsigned int lo = h[g_lo * 32 + wb * 2];
            unsigned int hi = h[g_lo * 32 + wb * 2 + 1];
            unsigned int outv = (lo & 0xffu) | (((lo >> 16) & 0xffu) << 8)
                              | ((hi & 0xffu) << 16) | (((hi >> 16) & 0xffu) << 24);
            int g = gc * 64 + g_lo;
            if (g < G_)
                fragw[(unsigned)g * 256u + (unsigned)cg * 16u + wb] = outv;
        }
    } else if (bid < 1536) {
        // ---- lwprep: bf16 transpose [g][n][64], k-pads zeroed ----
        for (int g = bid - 1280; g < G_; g += 256) {
            for (int r = t; r < L_ * K_; r += 256) {
                float v = lw[(size_t)g * (L_ * K_) + r];
                lwT[(size_t)g * 1024 + (r & 15) * 64 + (r >> 4)] =
                    __float2bfloat16(v);
            }
            for (int i = t; i < 16 * 14; i += 256) {
                int n = i / 14, l = 50 + (i % 14);
                lwT[(size_t)g * 1024 + n * 64 + l] = __float2bfloat16(0.f);
            }
        }
    } else {
        // ---- weight KL ----
        const int NTOT = G_ * L_ * K_ + G_ * L_;   // 850000
        int wb = bid - 1536;
        float s = 0.f;
        for (int i = wb * 256 + t; i < NTOT; i += 256 * 256) {
            float w = (i < G_ * L_ * K_) ? lw[i] : rw[i - G_ * L_ * K_];
            s += fmaf(-50.f * w, w, 1.3836465597893733f);
        }
        s = block_sum_256(s);
        if (t == 0) pb_wkl[wb] = -s;
    }
}

// --- 3. bn: reduce P (64 chunks) -> hT; write bnsum directly ---------------
__global__ __launch_bounds__(256)
void bn_kernel(const float* __restrict__ P,
               float* __restrict__ hT,
               double* __restrict__ bnsum) {
    int j = blockIdx.x;
    int t = threadIdx.x;
    float s1 = 0.f, s2 = 0.f;
#pragma unroll
    for (int u = 0; u < 4; ++u) {
        int c = u * 256 + t;
        float s = 0.f;
#pragma unroll 8
        for (int ch = 0; ch < 64; ++ch)
            s += P[(size_t)(ch * NHID_ + j) * C_ + c];
        hT[j * C_ + c] = s;
        s1 += s; s2 += s * s;
    }
    s1 = block_sum_256(s1);
    s2 = block_sum_256(s2);
    if (t == 0) { bnsum[j] = (double)s1; bnsum[NHID_ + j] = (double)s2; }
}

// --- 4. latent sample + KL -> partial; writes latT f32 + latbf bf16 + pads -
__global__ __launch_bounds__(256)
void latent_kernel(const float* __restrict__ hT,
                   const double* __restrict__ bnsum,
                   const float* __restrict__ gamma,
                   const float* __restrict__ beta,
                   const float* __restrict__ W_loc,   // [16][50]
                   const float* __restrict__ b_loc,
                   const float* __restrict__ W_scale, // [16][50]
                   const float* __restrict__ b_scale,
                   const float* __restrict__ eps,     // [1024][50]
                   float* __restrict__ latT,          // [50][1024]
                   __hip_bfloat16* __restrict__ latbf,// [1024][64]
                   float* __restrict__ pb) {          // [200]
    int idx = blockIdx.x * 256 + threadIdx.x;
    float kl = 0.f;
    {
        int c = idx / L_;
        int l = idx - c * L_;
        float hb[NHID_];
#pragma unroll
        for (int j = 0; j < NHID_; ++j) {
            float mean = (float)(bnsum[j] * (1.0 / C_));
            float ex2  = (float)(bnsum[NHID_ + j] * (1.0 / C_));
            float var = ex2 - mean * mean;
            float rstd = rsqrtf(var + 1e-5f);
            float sc = gamma[j] * rstd;
            float sh = beta[j] - mean * sc;
            float v = fmaf(hT[j * C_ + c], sc, sh);
            hb[j] = v > 0.f ? v : 0.f;
        }
        float loc = b_loc[l], ls = b_scale[l];
#pragma unroll
        for (int j = 0; j < NHID_; ++j) {
            loc = fmaf(hb[j], W_loc[j * L_ + l], loc);
            ls  = fmaf(hb[j], W_scale[j * L_ + l], ls);
        }
        float qs = 0.1f * __expf(ls);
        float e = eps[idx];
        float lat = fmaf(qs, e, loc);
        latT[(size_t)l * C_ + c] = lat;
        latbf[c * 64 + l] = __float2bfloat16(lat);
        if (l < 14) latbf[c * 64 + 50 + l] = __float2bfloat16(0.f);  // k-pad
        float z = (lat - loc) / qs;
        kl = fmaf(-0.5f * lat, lat, fmaf(0.5f * z, z, __logf(qs)));
    }
    float s = block_sum_256(kl);
    if (threadIdx.x == 0) pb[blockIdx.x] = -CELL_SCALE * s;
}

// --- 5. mixture (bf16 MFMA) + Poisson, one dispatch ------------------------
// grid (1000, 8): y<4 mixture cell-tile y; y>=4 Poisson cell-tile y-4.
__global__ __launch_bounds__(256)
void mixpois_kernel(const __hip_bfloat16* __restrict__ latbf, // [1024][64]
                    const __hip_bfloat16* __restrict__ lwT,   // [1000][16][64]
                    const unsigned int* __restrict__ merged,  // [16000][128]
                    const float* __restrict__ baseline,       // [1000][16]
                    const float* __restrict__ latT,           // [50][1024]
                    const float* __restrict__ rw,             // [1000][50]
                    const float* __restrict__ rho_bias,
                    const int* __restrict__ libsize,
                    const unsigned char* __restrict__ fragb,  // [1000][1024]
                    float* __restrict__ pb) {
    int g = blockIdx.x;
    if (blockIdx.y < 4) {
        int lane = threadIdx.x & 63;
        int wv = threadIdx.x >> 6;
        int n = lane & 15;
        int quad = lane >> 4;
        const __hip_bfloat16* bb = lwT + (size_t)g * 1024 + n * 64 + quad * 8;
        short8 b1 = *(const short8*)bb;
        short8 b2 = *(const short8*)(bb + 32);
        float bl = baseline[g * K_ + n];
        float partial = 0.f;
        int cwave = blockIdx.y * 256 + wv * 64;
#pragma unroll
        for (int mt = 0; mt < 4; ++mt) {
            int c0 = cwave + mt * 16;
            const __hip_bfloat16* aa = latbf + (size_t)(c0 + n) * 64 + quad * 8;
            short8 a1 = *(const short8*)aa;
            short8 a2 = *(const short8*)(aa + 32);
            f32x4 d = {bl, bl, bl, bl};
            d = __builtin_amdgcn_mfma_f32_16x16x32_bf16(a1, b1, d, 0, 0, 0);
            d = __builtin_amdgcn_mfma_f32_16x16x32_bf16(a2, b2, d, 0, 0, 0);
            float mx[4], ex[4];
#pragma unroll
            for (int r = 0; r < 4; ++r) mx[r] = d[r];
#pragma unroll
            for (int m = 1; m < 16; m <<= 1)
#pragma unroll
                for (int r = 0; r < 4; ++r)
                    mx[r] = fmaxf(mx[r], __shfl_xor(mx[r], m));
#pragma unroll
            for (int r = 0; r < 4; ++r) ex[r] = __expf(d[r] - mx[r]);
#pragma unroll
            for (int m = 1; m < 16; m <<= 1)
#pragma unroll
                for (int r = 0; r < 4; ++r) ex[r] += __shfl_xor(ex[r], m);
            int cp = c0 + quad * 4;
            unsigned int hw =
                merged[(unsigned)(g * K_ + n) * 128u + ((unsigned)cp >> 3)];
            int sb = (cp & 7) * 4;
#pragma unroll
            for (int r = 0; r < 4; ++r) {
                float lse = mx[r] + __logf(ex[r]);
                float cnt = (float)((hw >> (sb + r * 4)) & 0xfu);
                partial = fmaf(cnt, d[r] - lse, partial);
            }
        }
        float s = block_sum_256(-CUT_SCALE * partial);
        if (threadIdx.x == 0) pb[blockIdx.y * G_ + g] = s;
    } else {
        int yc = blockIdx.y - 4;
        int c = yc * 256 + threadIdx.x;
        const float* rwg = rw + (size_t)g * L_;   // hoists to SGPRs
        float rho = 0.f;
#pragma unroll 10
        for (int l = 0; l < L_; ++l)
            rho = fmaf(latT[l * C_ + c], rwg[l], rho);
        unsigned int fc = fragb[(size_t)g * C_ + c];
        float fe = rho_bias[g] * __expf(rho) * (float)libsize[c];
        float lf = fmaf((float)fc, __logf(fe), -fe) - LGT[fc > 31u ? 31u : fc];
        float s = block_sum_256(-CELL_SCALE * lf);
        if (threadIdx.x == 0) pb[NPB_MIX + yc * G_ + g] = s;
    }
}

// --- 6. finalize: f64-reduce all partials + constant -----------------------
__global__ __launch_bounds__(256)
void final_kernel(const float* __restrict__ pb, float* __restrict__ out) {
    __shared__ double sm[256];
    int t = threadIdx.x;
    double a = 0.0;
    for (int i = t; i < NPB_TOT; i += 256) a += (double)pb[i];
    sm[t] = a;
    __syncthreads();
#pragma unroll
    for (int s = 128; s > 0; s >>= 1) {
        if (t < s) sm[t] += sm[t + s];
        __syncthreads();
    }
    if (t == 0) out[0] = (float)(sm[0] - 138629436.11198905);  // -12.5*4e6*log16
}

extern "C" void kernel_launch(void* const* d_in, const int* in_sizes, int n_in,
                              void* d_out, int out_size, void* d_ws, size_t ws_size,
                              hipStream_t stream) {
    const float* cut_coord = (const float*)d_in[0];
    const float* eps       = (const float*)d_in[1];
    const float* enc_W1    = (const float*)d_in[2];
    // d_in[3] = enc_b1 : cancels through BatchNorm, unused
    const float* bn_gamma  = (const float*)d_in[4];
    const float* bn_beta   = (const float*)d_in[5];
    const float* W_loc     = (const float*)d_in[6];
    const float* b_loc     = (const float*)d_in[7];
    const float* W_scale   = (const float*)d_in[8];
    const float* b_scale   = (const float*)d_in[9];
    const float* logit_w   = (const float*)d_in[10];
    const float* rho_w     = (const float*)d_in[11];
    const float* baseline  = (const float*)d_in[12];
    const float* rho_bias  = (const float*)d_in[13];
    const int* cut_cxg     = (const int*)d_in[14];
    const int* frag_ix     = (const int*)d_in[16];
    const int* libsize     = (const int*)d_in[19];

    int n_cuts  = in_sizes[0];
    int n_frags = in_sizes[16];

    char* ws = (char*)d_ws;
    unsigned int*   gcnt_c = (unsigned int*)(ws + GCNTC_OFF);
    unsigned int*   gcnt_f = (unsigned int*)(ws + GCNTF_OFF);
    double*         bnsum  = (double*)(ws + BNSUM_OFF);
    __hip_bfloat16* latbf  = (__hip_bfloat16*)(ws + LATBF_OFF);
    __hip_bfloat16* lwT    = (__hip_bfloat16*)(ws + LWT_OFF);
    unsigned short* entc   = (unsigned short*)(ws + ENTC_OFF);
    unsigned short* entf   = (unsigned short*)(ws + ENTF_OFF);
    unsigned int*   merged = (unsigned int*)(ws + MERGED_OFF);
    unsigned int*   fragw  = (unsigned int*)(ws + FRAGU8_OFF);
    float*          P      = (float*)(ws + P_OFF);
    float*          hT     = (float*)(ws + HT_OFF);
    float*          latT   = (float*)(ws + LATT_OFF);
    float*          pb     = (float*)(ws + PB_OFF);
    float*          out    = (float*)d_out;

    int nblk_cut  = (n_cuts + 8191) / 8192;
    int nblk_frag = (n_frags + 8191) / 8192;

    hipMemsetAsync(ws, 0, ZERO_BYTES, stream);   // gcnt only

    part_kernel<<<nblk_cut + nblk_frag, 256, 0, stream>>>(
        cut_cxg, cut_coord, frag_ix, gcnt_c, gcnt_f, entc, entf,
        n_cuts, n_frags, nblk_cut);
    mid_kernel<<<1792, 256, 0, stream>>>(
        gcnt_c, entc, gcnt_f, entf, enc_W1, logit_w, rho_w,
        merged, fragw, P, lwT, pb + NPB_MIX + NPB_POIS);
    bn_kernel<<<NHID_, 256, 0, stream>>>(P, hT, bnsum);
    latent_kernel<<<(C_ * L_) / 256, 256, 0, stream>>>(
        hT, bnsum, bn_gamma, bn_beta, W_loc, b_loc, W_scale, b_scale,
        eps, latT, latbf, pb + NPB_MIX + NPB_POIS + NPB_WKL);
    mixpois_kernel<<<dim3(G_, 8), 256, 0, stream>>>(
        latbf, lwT, merged, baseline, latT, rho_w, rho_bias, libsize,
        (const unsigned char*)fragw, pb);
    final_kernel<<<1, 256, 0, stream>>>(pb, out);
}

// Round 13
// 244.994 us; speedup vs baseline: 1.6508x; 1.1275x over previous
//
#include <hip/hip_runtime.h>
#include <hip/hip_bf16.h>
#include <math.h>

// ---------------------------------------------------------------------------
// VAE ELBO (chromatin VAE). Sizes fixed by the reference.
//
//  * NB_ENC == NB_DEC == 16, identical binning => ONE nibble histogram serves
//    both the encoder input (log1p counts) and the mixture likelihood.
//  * r3-r5 (3x replicated): global atomics on gfx950 are memory-side ~32B RMW
//    => no per-record global atomics; two-phase LDS counting sort.
//  * r7: same-address atomics serialize ~16ns => per-block partial stores.
//  * r8: ~22us inter-dispatch gap => roles fused as block-ranges.
//  * r12 lesson: hipLaunchCooperativeKernel DOES NOT RUN under this harness
//    (output stayed zero) — multi-dispatch is the only path. Reverted.
//  * r13: part = register-staged single pass (6144 rec/block, 6xint4 +
//    6xfloat4 issued up-front, 12 loads in flight), lwprep+wkl ride in
//    part's grid (independent of partition); mid = hist+enc / frag only.
//  * Mixture logits = bf16 MFMA 16x16x32 (K padded 50->64); softmax over
//    components = shfl_xor across quad-group. Poisson uses log(n!) LUT.
// ---------------------------------------------------------------------------

#define G_      1000
#define C_      1024
#define L_      50
#define K_      16
#define NHID_   16
#define CUT_SCALE   12.5f          // N_TOTAL_CUTS / N_CUTS
#define CELL_SCALE  9.765625f      // N_TOTAL_CELLS / N_CELLS

#define CHUNK_    6144
#define RCAP_CUT  18432            // bucket capacity, cuts  (mean 16000)
#define RCAP_FRAG 9216             // bucket capacity, frags (mean 8000)

// partial buffer: mix[4000] | pois[4000] | wkl[256] | latent[200]
#define NPB_MIX  4000
#define NPB_POIS 4000
#define NPB_WKL  256
#define NPB_TOT  8456

// ws layout (bytes); only [0,2048) (gcnt) is memset per call.
#define GCNTC_OFF  0ull
#define GCNTF_OFF  1024ull
#define ZERO_BYTES 2048ull
#define BNSUM_OFF  2048ull         // f64[32], plain-written by bn
#define LATBF_OFF  2304ull         // bf16 [1024][64], pads written by latent
#define LWT_OFF    133376ull       // bf16 [1000][16][64], pads by lwprep
#define ENTC_OFF   2181376ull      // u16 [256][18432]
#define ENTF_OFF   11618560ull     // u16 [256][9216]
#define MERGED_OFF 16337152ull     // u32 [16000][128] nibble hist
#define FRAGU8_OFF 24529152ull     // u8  [1000][1024]
#define P_OFF      25577728ull     // f32 [64 chunk][16 j][1024 c]
#define HT_OFF     29772032ull     // f32 [16][1024]
#define LATT_OFF   29837568ull     // f32 [50][1024]
#define PB_OFF     30042368ull     // f32 [8456]
#define WS_NEED    30076192ull

typedef __attribute__((ext_vector_type(8))) short short8;
typedef __attribute__((ext_vector_type(4))) float f32x4;

__device__ __constant__ float LGT[32] = {   // log(n!)
    0.0f, 0.0f, 0.6931471805599453f, 1.791759469228055f, 3.1780538303479458f,
    4.787491742782046f, 6.579251212010101f, 8.525161361065415f,
    10.60460290274525f, 12.801827480081469f, 15.104412573075516f,
    17.502307845873887f, 19.987214495661885f, 22.552163853123425f,
    25.19122118273868f, 27.89927138384089f, 30.671860106080672f,
    33.50507345013689f, 36.39544520803305f, 39.339884187199495f,
    42.335616460753485f, 45.38013889847691f, 48.47118135183523f,
    51.60667556776438f, 54.78472939811232f, 58.00360522298052f,
    61.261701761002f, 64.55753862700633f, 67.88974313718154f,
    71.25703896716801f, 74.65823634883016f, 78.0922235533153f };

__device__ __forceinline__ float block_sum_256(float v) {
    __shared__ float sm[256];
    int t = threadIdx.x;
    __syncthreads();
    sm[t] = v;
    __syncthreads();
#pragma unroll
    for (int s = 128; s > 0; s >>= 1) {
        if (t < s) sm[t] += sm[t + s];
        __syncthreads();
    }
    return sm[0];
}

// --- 1. part: [0,nblk_part) radix partition (register-staged single pass) |
//        [nblk_part, +256) lwprep | [+256, +512) wkl ------------------------
__global__ __launch_bounds__(256)
void part_kernel(const int* __restrict__ cut_ix,
                 const float* __restrict__ coord,
                 const int* __restrict__ frag_ix,
                 unsigned int* __restrict__ gcnt_c,
                 unsigned int* __restrict__ gcnt_f,
                 unsigned short* __restrict__ entc,
                 unsigned short* __restrict__ entf,
                 const float* __restrict__ lw,      // [1000][50][16]
                 const float* __restrict__ rw,      // [1000][50]
                 __hip_bfloat16* __restrict__ lwT,  // [1000][16][64]
                 float* __restrict__ pb_wkl,        // [256]
                 int n_cuts, int n_frags, int ncc, int nblk_part) {
    int t = threadIdx.x;
    int bid = blockIdx.x;
    if (bid >= nblk_part) {
        int r = bid - nblk_part;
        if (r < 256) {
            // ---- lwprep: bf16 transpose [g][n][64], k-pads zeroed ----
            for (int g = r; g < G_; g += 256) {
                for (int i = t; i < L_ * K_; i += 256) {
                    float v = lw[(size_t)g * (L_ * K_) + i];
                    lwT[(size_t)g * 1024 + (i & 15) * 64 + (i >> 4)] =
                        __float2bfloat16(v);
                }
                for (int i = t; i < 16 * 14; i += 256) {
                    int n = i / 14, l = 50 + (i % 14);
                    lwT[(size_t)g * 1024 + n * 64 + l] = __float2bfloat16(0.f);
                }
            }
        } else {
            // ---- weight KL ----
            const int NTOT = G_ * L_ * K_ + G_ * L_;   // 850000
            int wb = r - 256;
            float s = 0.f;
            for (int i = wb * 256 + t; i < NTOT; i += 256 * 256) {
                float w = (i < G_ * L_ * K_) ? lw[i] : rw[i - G_ * L_ * K_];
                s += fmaf(-50.f * w, w, 1.3836465597893733f);
            }
            s = block_sum_256(s);
            if (t == 0) pb_wkl[wb] = -s;
        }
        return;
    }
    // ---- radix partition, one 6144-record chunk per block ----
    __shared__ unsigned int cnt[256], excl[256], cur[256], gbas[256];
    __shared__ unsigned short stage[CHUNK_];
    __shared__ unsigned char bkof[CHUNK_];
    bool isCut = (bid < ncc);
    int blk = isCut ? bid : bid - ncc;
    const int* idx = isCut ? cut_ix : frag_ix;
    int n = isCut ? n_cuts : n_frags;
    int rcap = isCut ? RCAP_CUT : RCAP_FRAG;
    unsigned int* gcount = isCut ? gcnt_c : gcnt_f;
    unsigned short* ent = isCut ? entc : entf;
    int i0 = blk * CHUNK_;
    cnt[t] = 0;
    // stage 24 records in registers: 6 int4 (+6 float4 for cuts), all in flight
    int4 I[6]; float4 X[6];
    unsigned int vm;
    bool full = (i0 + CHUNK_ <= n);
    if (full) {
        const int4* ip = (const int4*)(idx + i0);
#pragma unroll
        for (int k = 0; k < 6; ++k) I[k] = ip[k * 256 + t];
        if (isCut) {
            const float4* xp = (const float4*)(coord + i0);
#pragma unroll
            for (int k = 0; k < 6; ++k) X[k] = xp[k * 256 + t];
        }
        vm = 0xFFFFFFu;
    } else {
        vm = 0;
#pragma unroll
        for (int k = 0; k < 6; ++k) {
            int r0 = i0 + (k * 256 + t) * 4;
            int* Ii = (int*)&I[k]; float* Xi = (float*)&X[k];
#pragma unroll
            for (int u = 0; u < 4; ++u) {
                bool v = (r0 + u) < n;
                if (v) vm |= 1u << (k * 4 + u);
                Ii[u] = v ? idx[r0 + u] : 0;
                Xi[u] = (v && isCut) ? coord[r0 + u] : 0.f;
            }
        }
    }
    __syncthreads();
    // count
#pragma unroll
    for (int k = 0; k < 6; ++k) {
        const int* Ii = (const int*)&I[k];
        const float* Xi = (const float*)&X[k];
#pragma unroll
        for (int u = 0; u < 4; ++u) {
            if (vm & (1u << (k * 4 + u))) {
                int ix = Ii[u];
                int c = ix / G_;
                int g = ix - c * G_;
                unsigned int bk;
                if (isCut) {
                    int b = (int)(Xi[u] * 16.f); b = b > 15 ? 15 : b;
                    bk = ((unsigned)(c >> 6) << 4) | ((unsigned)(g * K_ + b) >> 10);
                } else {
                    bk = ((unsigned)(c >> 6) << 4) | ((unsigned)g >> 6);
                }
                atomicAdd(&cnt[bk], 1u);   // LDS atomic
            }
        }
    }
    __syncthreads();
    excl[t] = cnt[t];
    __syncthreads();
    for (int o = 1; o < 256; o <<= 1) {
        unsigned int v = (t >= o) ? excl[t - o] : 0u;
        __syncthreads();
        excl[t] += v;
        __syncthreads();
    }
    unsigned int my_excl = excl[t] - cnt[t];
    gbas[t] = cnt[t] ? atomicAdd(&gcount[t], cnt[t]) : 0u;  // global reserve
    cur[t] = my_excl;
    __syncthreads();
    excl[t] = my_excl;
    __syncthreads();
    // scatter from registers
#pragma unroll
    for (int k = 0; k < 6; ++k) {
        const int* Ii = (const int*)&I[k];
        const float* Xi = (const float*)&X[k];
#pragma unroll
        for (int u = 0; u < 4; ++u) {
            if (vm & (1u << (k * 4 + u))) {
                int ix = Ii[u];
                int c = ix / G_;
                int g = ix - c * G_;
                unsigned int bk; unsigned short e;
                if (isCut) {
                    int b = (int)(Xi[u] * 16.f); b = b > 15 ? 15 : b;
                    int bin = g * K_ + b;
                    bk = ((unsigned)(c >> 6) << 4) | ((unsigned)bin >> 10);
                    e = (unsigned short)(((c & 63) << 10) | (bin & 1023));
                } else {
                    bk = ((unsigned)(c >> 6) << 4) | ((unsigned)g >> 6);
                    e = (unsigned short)(((c & 63) << 6) | (g & 63));
                }
                unsigned int p = atomicAdd(&cur[bk], 1u);   // LDS atomic
                stage[p] = e;
                bkof[p] = (unsigned char)bk;
            }
        }
    }
    __syncthreads();
    int total = n - i0; if (total > CHUNK_) total = CHUNK_;
    for (int p = t; p < total; p += 256) {
        unsigned int bk = bkof[p];
        unsigned int dst = gbas[bk] + (p - excl[bk]);
        if (dst < (unsigned)rcap)
            ent[(size_t)bk * rcap + dst] = stage[p];
    }
}

// --- 2. mid kernel: [0,1024) quarter-bucket hist+enc | [1024,1280) frag ----
__global__ __launch_bounds__(256)
void mid_kernel(const unsigned int* __restrict__ gcnt_c,
                const unsigned short* __restrict__ entc,
                const unsigned int* __restrict__ gcnt_f,
                const unsigned short* __restrict__ entf,
                const float* __restrict__ W1,        // [16000][16]
                unsigned int* __restrict__ merged,   // [16000][128]
                unsigned int* __restrict__ fragw,    // u8[1000][1024] as u32
                float* __restrict__ P) {             // [64][16][1024]
    __shared__ unsigned int h[4096];   // 16 KB
    __shared__ float w1s[4096];        // 16 KB
    int t = threadIdx.x;
    int bid = blockIdx.x;
    if (bid < 1024) {
        // ---- quarter-bucket cut histogram + encoder partial ----
        int bk = bid >> 2, q = bid & 3;
        int cg = bk >> 4, bc = bk & 15;
        int wbase = (bc * 1024 + q * 256) * NHID_;
#pragma unroll
        for (int r = 0; r < 16; ++r) {
            int i = r * 256 + t;
            int gi = wbase + i;
            w1s[i] = (gi < 16000 * NHID_) ? W1[gi] : 0.f;
        }
        for (int i = t; i < 2048; i += 256) h[i] = 0;
        __syncthreads();
        unsigned int count = gcnt_c[bk];
        if (count > RCAP_CUT) count = RCAP_CUT;
        const unsigned int* e32 = (const unsigned int*)(entc + (size_t)bk * RCAP_CUT);
        unsigned int npair = count >> 1;
        for (unsigned int base = 0; base < npair; base += 1024) {
            unsigned int w[4]; bool val[4];
#pragma unroll
            for (int u = 0; u < 4; ++u) {
                unsigned int p = base + u * 256 + t;
                val[u] = (p < npair);
                w[u] = val[u] ? e32[p] : 0u;
            }
#pragma unroll
            for (int u = 0; u < 4; ++u) {
                if (val[u]) {
                    unsigned int v0 = w[u] & 0xffffu, v1 = w[u] >> 16;
                    unsigned int b0 = v0 & 1023u, b1 = v1 & 1023u;
                    if ((int)(b0 >> 8) == q) {
                        unsigned int c0 = v0 >> 10;
                        atomicAdd(&h[(b0 & 255u) * 8 + (c0 >> 3)],
                                  1u << ((c0 & 7) * 4));
                    }
                    if ((int)(b1 >> 8) == q) {
                        unsigned int c1 = v1 >> 10;
                        atomicAdd(&h[(b1 & 255u) * 8 + (c1 >> 3)],
                                  1u << ((c1 & 7) * 4));
                    }
                }
            }
        }
        if (t == 0 && (count & 1u)) {
            unsigned int v = ((const unsigned short*)e32)[count - 1];
            unsigned int b0 = v & 1023u;
            if ((int)(b0 >> 8) == q) {
                unsigned int c0 = v >> 10;
                atomicAdd(&h[(b0 & 255u) * 8 + (c0 >> 3)], 1u << ((c0 & 7) * 4));
            }
        }
        __syncthreads();
        for (int i = t; i < 2048; i += 256) {
            int bin = bc * 1024 + q * 256 + (i >> 3);
            if (bin < 16000)
                merged[(unsigned)bin * 128u + (unsigned)cg * 8u + (i & 7)] = h[i];
        }
        // enc: W1 from LDS broadcast
        int c_lo = t & 63, sub = t >> 6;
        float acc[NHID_];
#pragma unroll
        for (int j = 0; j < NHID_; ++j) acc[j] = 0.f;
        int rbase = bc * 1024 + q * 256 + sub * 64;
        int sh = (c_lo & 7) * 4;
        const float4* w1v = (const float4*)w1s;
#pragma unroll 2
        for (int bl = 0; bl < 64; ++bl) {
            int row = rbase + bl;
            if (row < 16000) {   // wave-uniform
                int rl = sub * 64 + bl;
                unsigned int w = h[rl * 8 + (c_lo >> 3)];
                float xv = __logf((float)(((w >> sh) & 0xfu) + 1u));
                float4 wa = w1v[rl * 4 + 0];
                float4 wb = w1v[rl * 4 + 1];
                float4 wc = w1v[rl * 4 + 2];
                float4 wd = w1v[rl * 4 + 3];
                acc[0] = fmaf(xv, wa.x, acc[0]);  acc[1] = fmaf(xv, wa.y, acc[1]);
                acc[2] = fmaf(xv, wa.z, acc[2]);  acc[3] = fmaf(xv, wa.w, acc[3]);
                acc[4] = fmaf(xv, wb.x, acc[4]);  acc[5] = fmaf(xv, wb.y, acc[5]);
                acc[6] = fmaf(xv, wb.z, acc[6]);  acc[7] = fmaf(xv, wb.w, acc[7]);
                acc[8] = fmaf(xv, wc.x, acc[8]);  acc[9] = fmaf(xv, wc.y, acc[9]);
                acc[10] = fmaf(xv, wc.z, acc[10]); acc[11] = fmaf(xv, wc.w, acc[11]);
                acc[12] = fmaf(xv, wd.x, acc[12]); acc[13] = fmaf(xv, wd.y, acc[13]);
                acc[14] = fmaf(xv, wd.z, acc[14]); acc[15] = fmaf(xv, wd.w, acc[15]);
            }
        }
        __syncthreads();
        float* sp = (float*)h;
#pragma unroll
        for (int j = 0; j < NHID_; ++j) sp[sub * 1024 + j * 64 + c_lo] = acc[j];
        __syncthreads();
        for (int i = t; i < 1024; i += 256) {
            int j = i >> 6, c = i & 63;
            float v = sp[j * 64 + c] + sp[1024 + j * 64 + c]
                    + sp[2048 + j * 64 + c] + sp[3072 + j * 64 + c];
            P[(size_t)((bc * 4 + q) * NHID_ + j) * C_ + cg * 64 + c] = v;
        }
    } else {
        // ---- per-bucket frag counts -> u8 ----
        int bk = bid - 1024, cg = bk >> 4, gc = bk & 15;
        for (int i = t; i < 2048; i += 256) h[i] = 0;
        __syncthreads();
        unsigned int count = gcnt_f[bk];
        if (count > RCAP_FRAG) count = RCAP_FRAG;
        const unsigned short* e = entf + (size_t)bk * RCAP_FRAG;
#pragma unroll 4
        for (unsigned int p = t; p < count; p += 256) {
            unsigned int v = e[p];
            unsigned int g_lo = v & 63u;
            unsigned int c_lo = v >> 6;
            atomicAdd(&h[g_lo * 32 + (c_lo >> 1)], 1u << ((c_lo & 1) * 16));
        }
        __syncthreads();
        for (int i = t; i < 1024; i += 256) {
            int g_lo = i >> 4, wb = i & 15;
            unsigned int lo = h[g_lo * 32 + wb * 2];
            unsigned int hi = h[g_lo * 32 + wb * 2 + 1];
            unsigned int outv = (lo & 0xffu) | (((lo >> 16) & 0xffu) << 8)
                              | ((hi & 0xffu) << 16) | (((hi >> 16) & 0xffu) << 24);
            int g = gc * 64 + g_lo;
            if (g < G_)
                fragw[(unsigned)g * 256u + (unsigned)cg * 16u + wb] = outv;
        }
    }
}

// --- 3. bn: reduce P (64 chunks) -> hT; write bnsum directly ---------------
__global__ __launch_bounds__(256)
void bn_kernel(const float* __restrict__ P,
               float* __restrict__ hT,
               double* __restrict__ bnsum) {
    int j = blockIdx.x;
    int t = threadIdx.x;
    float s1 = 0.f, s2 = 0.f;
#pragma unroll
    for (int u = 0; u < 4; ++u) {
        int c = u * 256 + t;
        float s = 0.f;
#pragma unroll 8
        for (int ch = 0; ch < 64; ++ch)
            s += P[(size_t)(ch * NHID_ + j) * C_ + c];
        hT[j * C_ + c] = s;
        s1 += s; s2 += s * s;
    }
    s1 = block_sum_256(s1);
    s2 = block_sum_256(s2);
    if (t == 0) { bnsum[j] = (double)s1; bnsum[NHID_ + j] = (double)s2; }
}

// --- 4. latent sample + KL -> partial; writes latT f32 + latbf bf16 + pads -
__global__ __launch_bounds__(256)
void latent_kernel(const float* __restrict__ hT,
                   const double* __restrict__ bnsum,
                   const float* __restrict__ gamma,
                   const float* __restrict__ beta,
                   const float* __restrict__ W_loc,   // [16][50]
                   const float* __restrict__ b_loc,
                   const float* __restrict__ W_scale, // [16][50]
                   const float* __restrict__ b_scale,
                   const float* __restrict__ eps,     // [1024][50]
                   float* __restrict__ latT,          // [50][1024]
                   __hip_bfloat16* __restrict__ latbf,// [1024][64]
                   float* __restrict__ pb) {          // [200]
    int idx = blockIdx.x * 256 + threadIdx.x;
    float kl = 0.f;
    {
        int c = idx / L_;
        int l = idx - c * L_;
        float hb[NHID_];
#pragma unroll
        for (int j = 0; j < NHID_; ++j) {
            float mean = (float)(bnsum[j] * (1.0 / C_));
            float ex2  = (float)(bnsum[NHID_ + j] * (1.0 / C_));
            float var = ex2 - mean * mean;
            float rstd = rsqrtf(var + 1e-5f);
            float sc = gamma[j] * rstd;
            float sh = beta[j] - mean * sc;
            float v = fmaf(hT[j * C_ + c], sc, sh);
            hb[j] = v > 0.f ? v : 0.f;
        }
        float loc = b_loc[l], ls = b_scale[l];
#pragma unroll
        for (int j = 0; j < NHID_; ++j) {
            loc = fmaf(hb[j], W_loc[j * L_ + l], loc);
            ls  = fmaf(hb[j], W_scale[j * L_ + l], ls);
        }
        float qs = 0.1f * __expf(ls);
        float e = eps[idx];
        float lat = fmaf(qs, e, loc);
        latT[(size_t)l * C_ + c] = lat;
        latbf[c * 64 + l] = __float2bfloat16(lat);
        if (l < 14) latbf[c * 64 + 50 + l] = __float2bfloat16(0.f);  // k-pad
        float z = (lat - loc) / qs;
        kl = fmaf(-0.5f * lat, lat, fmaf(0.5f * z, z, __logf(qs)));
    }
    float s = block_sum_256(kl);
    if (threadIdx.x == 0) pb[blockIdx.x] = -CELL_SCALE * s;
}

// --- 5. mixture (bf16 MFMA) + Poisson, one dispatch ------------------------
// grid (1000, 8): y<4 mixture cell-tile y; y>=4 Poisson cell-tile y-4.
__global__ __launch_bounds__(256)
void mixpois_kernel(const __hip_bfloat16* __restrict__ latbf, // [1024][64]
                    const __hip_bfloat16* __restrict__ lwT,   // [1000][16][64]
                    const unsigned int* __restrict__ merged,  // [16000][128]
                    const float* __restrict__ baseline,       // [1000][16]
                    const float* __restrict__ latT,           // [50][1024]
                    const float* __restrict__ rw,             // [1000][50]
                    const float* __restrict__ rho_bias,
                    const int* __restrict__ libsize,
                    const unsigned char* __restrict__ fragb,  // [1000][1024]
                    float* __restrict__ pb) {
    int g = blockIdx.x;
    if (blockIdx.y < 4) {
        int lane = threadIdx.x & 63;
        int wv = threadIdx.x >> 6;
        int n = lane & 15;
        int quad = lane >> 4;
        const __hip_bfloat16* bb = lwT + (size_t)g * 1024 + n * 64 + quad * 8;
        short8 b1 = *(const short8*)bb;
        short8 b2 = *(const short8*)(bb + 32);
        float bl = baseline[g * K_ + n];
        float partial = 0.f;
        int cwave = blockIdx.y * 256 + wv * 64;
#pragma unroll
        for (int mt = 0; mt < 4; ++mt) {
            int c0 = cwave + mt * 16;
            const __hip_bfloat16* aa = latbf + (size_t)(c0 + n) * 64 + quad * 8;
            short8 a1 = *(const short8*)aa;
            short8 a2 = *(const short8*)(aa + 32);
            f32x4 d = {bl, bl, bl, bl};
            d = __builtin_amdgcn_mfma_f32_16x16x32_bf16(a1, b1, d, 0, 0, 0);
            d = __builtin_amdgcn_mfma_f32_16x16x32_bf16(a2, b2, d, 0, 0, 0);
            float mx[4], ex[4];
#pragma unroll
            for (int r = 0; r < 4; ++r) mx[r] = d[r];
#pragma unroll
            for (int m = 1; m < 16; m <<= 1)
#pragma unroll
                for (int r = 0; r < 4; ++r)
                    mx[r] = fmaxf(mx[r], __shfl_xor(mx[r], m));
#pragma unroll
            for (int r = 0; r < 4; ++r) ex[r] = __expf(d[r] - mx[r]);
#pragma unroll
            for (int m = 1; m < 16; m <<= 1)
#pragma unroll
                for (int r = 0; r < 4; ++r) ex[r] += __shfl_xor(ex[r], m);
            int cp = c0 + quad * 4;
            unsigned int hw =
                merged[(unsigned)(g * K_ + n) * 128u + ((unsigned)cp >> 3)];
            int sb = (cp & 7) * 4;
#pragma unroll
            for (int r = 0; r < 4; ++r) {
                float lse = mx[r] + __logf(ex[r]);
                float cnt = (float)((hw >> (sb + r * 4)) & 0xfu);
                partial = fmaf(cnt, d[r] - lse, partial);
            }
        }
        float s = block_sum_256(-CUT_SCALE * partial);
        if (threadIdx.x == 0) pb[blockIdx.y * G_ + g] = s;
    } else {
        int yc = blockIdx.y - 4;
        int c = yc * 256 + threadIdx.x;
        const float* rwg = rw + (size_t)g * L_;   // hoists to SGPRs
        float rho = 0.f;
#pragma unroll 10
        for (int l = 0; l < L_; ++l)
            rho = fmaf(latT[l * C_ + c], rwg[l], rho);
        unsigned int fc = fragb[(size_t)g * C_ + c];
        float fe = rho_bias[g] * __expf(rho) * (float)libsize[c];
        float lf = fmaf((float)fc, __logf(fe), -fe) - LGT[fc > 31u ? 31u : fc];
        float s = block_sum_256(-CELL_SCALE * lf);
        if (threadIdx.x == 0) pb[NPB_MIX + yc * G_ + g] = s;
    }
}

// --- 6. finalize: f64-reduce all partials + constant -----------------------
__global__ __launch_bounds__(256)
void final_kernel(const float* __restrict__ pb, float* __restrict__ out) {
    __shared__ double sm[256];
    int t = threadIdx.x;
    double a = 0.0;
    for (int i = t; i < NPB_TOT; i += 256) a += (double)pb[i];
    sm[t] = a;
    __syncthreads();
#pragma unroll
    for (int s = 128; s > 0; s >>= 1) {
        if (t < s) sm[t] += sm[t + s];
        __syncthreads();
    }
    if (t == 0) out[0] = (float)(sm[0] - 138629436.11198905);  // -12.5*4e6*log16
}

extern "C" void kernel_launch(void* const* d_in, const int* in_sizes, int n_in,
                              void* d_out, int out_size, void* d_ws, size_t ws_size,
                              hipStream_t stream) {
    const float* cut_coord = (const float*)d_in[0];
    const float* eps       = (const float*)d_in[1];
    const float* enc_W1    = (const float*)d_in[2];
    // d_in[3] = enc_b1 : cancels through BatchNorm, unused
    const float* bn_gamma  = (const float*)d_in[4];
    const float* bn_beta   = (const float*)d_in[5];
    const float* W_loc     = (const float*)d_in[6];
    const float* b_loc     = (const float*)d_in[7];
    const float* W_scale   = (const float*)d_in[8];
    const float* b_scale   = (const float*)d_in[9];
    const float* logit_w   = (const float*)d_in[10];
    const float* rho_w     = (const float*)d_in[11];
    const float* baseline  = (const float*)d_in[12];
    const float* rho_bias  = (const float*)d_in[13];
    const int* cut_cxg     = (const int*)d_in[14];
    const int* frag_ix     = (const int*)d_in[16];
    const int* libsize     = (const int*)d_in[19];

    int n_cuts  = in_sizes[0];
    int n_frags = in_sizes[16];

    char* ws = (char*)d_ws;
    unsigned int*   gcnt_c = (unsigned int*)(ws + GCNTC_OFF);
    unsigned int*   gcnt_f = (unsigned int*)(ws + GCNTF_OFF);
    double*         bnsum  = (double*)(ws + BNSUM_OFF);
    __hip_bfloat16* latbf  = (__hip_bfloat16*)(ws + LATBF_OFF);
    __hip_bfloat16* lwT    = (__hip_bfloat16*)(ws + LWT_OFF);
    unsigned short* entc   = (unsigned short*)(ws + ENTC_OFF);
    unsigned short* entf   = (unsigned short*)(ws + ENTF_OFF);
    unsigned int*   merged = (unsigned int*)(ws + MERGED_OFF);
    unsigned int*   fragw  = (unsigned int*)(ws + FRAGU8_OFF);
    float*          P      = (float*)(ws + P_OFF);
    float*          hT     = (float*)(ws + HT_OFF);
    float*          latT   = (float*)(ws + LATT_OFF);
    float*          pb     = (float*)(ws + PB_OFF);
    float*          out    = (float*)d_out;

    int ncc = (n_cuts + CHUNK_ - 1) / CHUNK_;
    int ncf = (n_frags + CHUNK_ - 1) / CHUNK_;
    int nblk_part = ncc + ncf;

    hipMemsetAsync(ws, 0, ZERO_BYTES, stream);   // gcnt only

    part_kernel<<<nblk_part + 512, 256, 0, stream>>>(
        cut_cxg, cut_coord, frag_ix, gcnt_c, gcnt_f, entc, entf,
        logit_w, rho_w, lwT, pb + NPB_MIX + NPB_POIS,
        n_cuts, n_frags, ncc, nblk_part);
    mid_kernel<<<1280, 256, 0, stream>>>(
        gcnt_c, entc, gcnt_f, entf, enc_W1, merged, fragw, P);
    bn_kernel<<<NHID_, 256, 0, stream>>>(P, hT, bnsum);
    latent_kernel<<<(C_ * L_) / 256, 256, 0, stream>>>(
        hT, bnsum, bn_gamma, bn_beta, W_loc, b_loc, W_scale, b_scale,
        eps, latT, latbf, pb + NPB_MIX + NPB_POIS + NPB_WKL);
    mixpois_kernel<<<dim3(G_, 8), 256, 0, stream>>>(
        latbf, lwT, merged, baseline, latT, rho_w, rho_bias, libsize,
        (const unsigned char*)fragw, pb);
    final_kernel<<<1, 256, 0, stream>>>(pb, out);
}